// Round 1
// baseline (1362.644 us; speedup 1.0000x reference)
//
#include <hip/hip_runtime.h>
#include <hip/hip_bf16.h>
#include <math.h>

// Problem constants
#define NN 20000
#define MM 20          // neighbors (same for che and vdw)
#define EE 20          // RBF size
#define HH 128
#define BB 200
#define NCONV 3
#define CHE_CUT 8.0f
#define VDW_CUT 12.0f
#define PI_F 3.14159265358979323846f

// ---------------- activation helpers (fp32, loose 2% threshold) -------------
__device__ __forceinline__ float sp_(float x) {
    // softplus = log1p(exp(x)); for x>15 the correction < 3e-7
    return (x > 15.f) ? x : __logf(1.f + __expf(x));
}
__device__ __forceinline__ float sig_(float x) {
    return 1.f / (1.f + __expf(-x));
}

// ---------------- prep: Wc = fW @ gW_edge, bc = gb + fb @ gW_edge -----------
// grid (EE+1, 2, NCONV), block 256 (j over 2H)
__global__ void prep_wc(const float* __restrict__ cfW, const float* __restrict__ cfb,
                        const float* __restrict__ cgW, const float* __restrict__ cgb,
                        const float* __restrict__ vfW, const float* __restrict__ vfb,
                        const float* __restrict__ vgW, const float* __restrict__ vgb,
                        float* __restrict__ wc, float* __restrict__ bc) {
    int e = blockIdx.x;          // 0..EE (EE == bias slot)
    int half = blockIdx.y;       // 0=che 1=vdw
    int l = blockIdx.z;
    int j = threadIdx.x;         // 0..255
    const float* fW = half ? vfW : cfW;   // [NCONV, EE, HH]
    const float* fb = half ? vfb : cfb;   // [NCONV, HH]
    const float* gW = half ? vgW : cgW;   // [NCONV, 3H, 2H]
    const float* gb = half ? vgb : cgb;   // [NCONV, 2H]
    const float* gWe = gW + ((size_t)l * 384 + 128) * 256;  // edge rows 128..255
    if (e < EE) {
        const float* frow = fW + ((size_t)l * EE + e) * HH;
        float acc = 0.f;
        for (int k = 0; k < HH; ++k) acc = fmaf(frow[k], gWe[k * 256 + j], acc);
        wc[(((size_t)l * 2 + half) * EE + e) * 256 + j] = acc;
    } else {
        const float* brow = fb + (size_t)l * HH;
        float acc = gb[(size_t)l * 256 + j];
        for (int k = 0; k < HH; ++k) acc = fmaf(brow[k], gWe[k * 256 + j], acc);
        bc[((size_t)l * 2 + half) * 256 + j] = acc;
    }
}

// ---------------- prep: Wbig [NCONV][128][1024] -----------------------------
// cols: [che_self(256) | che_nbr(256) | vdw_self(256) | vdw_nbr(256)]
__global__ void prep_wbig(const float* __restrict__ cgW, const float* __restrict__ vgW,
                          float* __restrict__ wbig) {
    int i = blockIdx.x * 256 + threadIdx.x;
    if (i >= NCONV * 128 * 1024) return;
    int l = i >> 17;
    int rem = i & 131071;
    int k = rem >> 10;         // 0..127
    int j = rem & 1023;
    int half = j >> 9, part = (j >> 8) & 1, col = j & 255;
    const float* src = half ? vgW : cgW;
    wbig[i] = src[((size_t)l * 384 + (part ? 256 : 0) + k) * 256 + col];
}

// ---------------- embed: nodes0 = atoms_embed @ emb_W + emb_b ---------------
__global__ void embed_kernel(const float* __restrict__ atoms, const float* __restrict__ W,
                             const float* __restrict__ bias, float* __restrict__ nodes) {
    int n = blockIdx.x, t = threadIdx.x;
    const float* arow = atoms + (size_t)n * 13;   // uniform per block -> s_load
    float acc = bias[t];
    #pragma unroll
    for (int k = 0; k < 13; ++k) acc = fmaf(arow[k], W[k * HH + t], acc);
    nodes[(size_t)n * HH + t] = acc;
}

// ---------------- rbf: sinc basis * cosine envelope -------------------------
__global__ void rbf_kernel(const float* __restrict__ fea, float* __restrict__ rbf,
                           int total, float cutoff) {
    int i = blockIdx.x * blockDim.x + threadIdx.x;
    if (i >= total) return;
    float d = fea[i];
    float x = d * (PI_F / cutoff);
    float s1 = sinf(x), c1 = cosf(x);
    float env = 0.5f * (c1 + 1.f);
    float scale = (d < cutoff) ? (env / d) : 0.f;
    float out[EE];
    float skm1 = 0.f, sk = s1;    // sin(k x) via Chebyshev recurrence
    #pragma unroll
    for (int e = 0; e < EE; ++e) {
        out[e] = sk * scale;
        float nx = 2.f * c1 * sk - skm1;
        skm1 = sk; sk = nx;
    }
    float4* dst = (float4*)(rbf + (size_t)i * EE);   // 80B stride -> 16B aligned
    #pragma unroll
    for (int q = 0; q < 5; ++q) dst[q] = ((const float4*)out)[q];
}

// ---------------- SY GEMM: [N,128] @ [128,1024] -----------------------------
// block 256 threads, 64x64 tile, 4x4 per thread, KC=32
__global__ void gemm_sy(const float* __restrict__ A, const float* __restrict__ B,
                        float* __restrict__ C, int M) {
    __shared__ float As[32][68];   // padded: conflict-lite store, aligned f4 read
    __shared__ float Bs[32][64];
    int bm = blockIdx.y * 64;
    int bn = blockIdx.x * 64;
    int tid = threadIdx.x;
    int tx = tid & 15, ty = tid >> 4;
    float acc[4][4] = {};
    for (int kc = 0; kc < 128; kc += 32) {
        {
            int k = tid & 31, r0 = tid >> 5;     // A: transpose-stage 64 rows x 32 k
            #pragma unroll
            for (int rr = 0; rr < 8; ++rr) {
                int r = r0 + rr * 8;
                int row = bm + r; if (row >= M) row = M - 1;
                As[k][r] = A[(size_t)row * 128 + kc + k];
            }
            int c = tid & 63, k0 = tid >> 6;     // B: 32 k x 64 cols
            #pragma unroll
            for (int kk = 0; kk < 8; ++kk) {
                int k2 = k0 + kk * 4;
                Bs[k2][c] = B[(size_t)(kc + k2) * 1024 + bn + c];
            }
        }
        __syncthreads();
        #pragma unroll
        for (int k = 0; k < 32; ++k) {
            float4 av = *(const float4*)&As[k][ty * 4];
            float4 bv = *(const float4*)&Bs[k][tx * 4];
            float a_[4] = {av.x, av.y, av.z, av.w};
            float b_[4] = {bv.x, bv.y, bv.z, bv.w};
            #pragma unroll
            for (int i = 0; i < 4; ++i)
                #pragma unroll
                for (int j = 0; j < 4; ++j)
                    acc[i][j] = fmaf(a_[i], b_[j], acc[i][j]);
        }
        __syncthreads();
    }
    #pragma unroll
    for (int i = 0; i < 4; ++i) {
        int row = bm + ty * 4 + i;
        if (row < M)
            #pragma unroll
            for (int j = 0; j < 4; ++j)
                C[(size_t)row * 1024 + bn + tx * 4 + j] = acc[i][j];
    }
}

// ---------------- fused edge + gate + node update ---------------------------
// SY layout per node: [S_che(0:256) | Y_che(256:512) | S_vdw(512:768) | Y_vdw(768:1024)]
// block = 128 threads (2 waves), one node stream -> n uniform -> rbf/idx s_loads
#define NODES_SEQ 8
__global__ void edge_kernel(const float* __restrict__ nodes_in, float* __restrict__ nodes_out,
                            const float* __restrict__ SY,
                            const float* __restrict__ rbf_che, const float* __restrict__ rbf_vdw,
                            const int* __restrict__ idx_che, const int* __restrict__ idx_vdw,
                            const float* __restrict__ Wc,   // [2][EE][256] this layer
                            const float* __restrict__ bC) { // [2][256]
    int t = threadIdx.x;
    float wcf[EE], wcc[EE], wvf[EE], wvc[EE];
    #pragma unroll
    for (int e = 0; e < EE; ++e) {
        wcf[e] = Wc[e * 256 + t];
        wcc[e] = Wc[e * 256 + 128 + t];
        wvf[e] = Wc[EE * 256 + e * 256 + t];
        wvc[e] = Wc[EE * 256 + e * 256 + 128 + t];
    }
    float bcf = bC[t], bcc = bC[128 + t], bvf = bC[256 + t], bvc = bC[384 + t];

    for (int s = 0; s < NODES_SEQ; ++s) {
        int n = blockIdx.x * NODES_SEQ + s;
        const float* syn = SY + (size_t)n * 1024;
        float sCf = syn[t], sCc = syn[128 + t];
        float sVf = syn[512 + t], sVc = syn[640 + t];
        float accC = 0.f, accV = 0.f;
        const int* ic = idx_che + (size_t)n * MM;
        const int* iv = idx_vdw + (size_t)n * MM;
        const float* rc = rbf_che + (size_t)n * MM * EE;
        const float* rv = rbf_vdw + (size_t)n * MM * EE;

        for (int m = 0; m < MM; ++m) {
            int j = ic[m];                             // uniform -> s_load
            const float* y = SY + (size_t)j * 1024 + 256;
            float gf = sCf + bcf + y[t];
            float gc = sCc + bcc + y[128 + t];
            const float* r = rc + m * EE;              // uniform -> s_load
            #pragma unroll
            for (int e = 0; e < EE; ++e) {
                gf = fmaf(r[e], wcf[e], gf);
                gc = fmaf(r[e], wcc[e], gc);
            }
            accC += sig_(gf) * sp_(gc);
        }
        for (int m = 0; m < MM; ++m) {
            int j = iv[m];
            const float* y = SY + (size_t)j * 1024 + 768;
            float gf = sVf + bvf + y[t];
            float gc = sVc + bvc + y[128 + t];
            const float* r = rv + m * EE;
            #pragma unroll
            for (int e = 0; e < EE; ++e) {
                gf = fmaf(r[e], wvf[e], gf);
                gc = fmaf(r[e], wvc[e], gc);
            }
            accV += sig_(gf) * sp_(gc);
        }
        float old = nodes_in[(size_t)n * HH + t];
        nodes_out[(size_t)n * HH + t] = sp_(old + accC + accV);
    }
}

// ---------------- pooling + head MLP ---------------------------------------
__global__ void pool_kernel(const float* __restrict__ nodes, const int* __restrict__ num_atoms,
                            const float* __restrict__ fc1_W, const float* __restrict__ fc1_b,
                            const float* __restrict__ out_W, const float* __restrict__ out_b,
                            float* __restrict__ out) {
    __shared__ float sh[HH];
    __shared__ float red[HH];
    int b = blockIdx.x, t = threadIdx.x;
    int start = 0;
    for (int i = 0; i < b; ++i) start += num_atoms[i];
    int cnt = num_atoms[b];
    float sum = 0.f;
    for (int a = 0; a < cnt; ++a) sum += nodes[(size_t)(start + a) * HH + t];
    float mean = sum / (float)cnt;
    sh[t] = sp_(mean);
    __syncthreads();
    float o = fc1_b[t];
    #pragma unroll 4
    for (int k = 0; k < HH; ++k) o = fmaf(sh[k], fc1_W[k * HH + t], o);
    red[t] = sp_(o) * out_W[t];
    __syncthreads();
    if (t == 0) {
        float tot = 0.f;
        for (int k = 0; k < HH; ++k) tot += red[k];
        out[b] = tot + out_b[0];
    }
}

// ---------------- launch ----------------------------------------------------
extern "C" void kernel_launch(void* const* d_in, const int* in_sizes, int n_in,
                              void* d_out, int out_size, void* d_ws, size_t ws_size,
                              hipStream_t stream) {
    const float* atoms_embed   = (const float*)d_in[0];
    const float* che_nbrs_fea  = (const float*)d_in[1];
    const float* vdw_nbrs_fea  = (const float*)d_in[2];
    const int*   che_nbrs_idx  = (const int*)  d_in[3];
    const int*   vdw_nbrs_idx  = (const int*)  d_in[4];
    const int*   num_atoms     = (const int*)  d_in[5];
    const float* emb_W         = (const float*)d_in[6];
    const float* emb_b         = (const float*)d_in[7];
    const float* che_filter_W  = (const float*)d_in[8];
    const float* che_filter_b  = (const float*)d_in[9];
    const float* che_fc_W      = (const float*)d_in[10];
    const float* che_fc_b      = (const float*)d_in[11];
    const float* vdw_filter_W  = (const float*)d_in[12];
    const float* vdw_filter_b  = (const float*)d_in[13];
    const float* vdw_fc_W      = (const float*)d_in[14];
    const float* vdw_fc_b      = (const float*)d_in[15];
    const float* fc1_W         = (const float*)d_in[16];
    const float* fc1_b         = (const float*)d_in[17];
    const float* out_W         = (const float*)d_in[18];
    const float* out_b         = (const float*)d_in[19];
    float* out = (float*)d_out;

    // workspace layout (floats). total ~168.1 MB
    float* w = (float*)d_ws;
    float* nodesA  = w;                          // 2,560,000
    float* nodesB  = nodesA + (size_t)NN * HH;   // 2,560,000
    float* SY      = nodesB + (size_t)NN * HH;   // 20,480,000
    float* rbf_che = SY + (size_t)NN * 1024;     // 8,000,000
    float* rbf_vdw = rbf_che + (size_t)NN * MM * EE;
    float* wbig    = rbf_vdw + (size_t)NN * MM * EE;      // 393,216
    float* wc      = wbig + (size_t)NCONV * 128 * 1024;   // 30,720
    float* bc      = wc + (size_t)NCONV * 2 * EE * 256;   // 1,536

    prep_wc<<<dim3(EE + 1, 2, NCONV), 256, 0, stream>>>(
        che_filter_W, che_filter_b, che_fc_W, che_fc_b,
        vdw_filter_W, vdw_filter_b, vdw_fc_W, vdw_fc_b, wc, bc);
    prep_wbig<<<(NCONV * 128 * 1024 + 255) / 256, 256, 0, stream>>>(che_fc_W, vdw_fc_W, wbig);
    embed_kernel<<<NN, HH, 0, stream>>>(atoms_embed, emb_W, emb_b, nodesA);
    rbf_kernel<<<(NN * MM + 255) / 256, 256, 0, stream>>>(che_nbrs_fea, rbf_che, NN * MM, CHE_CUT);
    rbf_kernel<<<(NN * MM + 255) / 256, 256, 0, stream>>>(vdw_nbrs_fea, rbf_vdw, NN * MM, VDW_CUT);

    float* cur = nodesA;
    float* nxt = nodesB;
    for (int l = 0; l < NCONV; ++l) {
        gemm_sy<<<dim3(16, (NN + 63) / 64), 256, 0, stream>>>(cur, wbig + (size_t)l * 128 * 1024, SY, NN);
        edge_kernel<<<NN / NODES_SEQ, HH, 0, stream>>>(
            cur, nxt, SY, rbf_che, rbf_vdw, che_nbrs_idx, vdw_nbrs_idx,
            wc + (size_t)l * 2 * EE * 256, bc + (size_t)l * 2 * 256);
        float* tmp = cur; cur = nxt; nxt = tmp;
    }

    pool_kernel<<<BB, HH, 0, stream>>>(cur, num_atoms, fc1_W, fc1_b, out_W, out_b, out);
}

// Round 2
// 1313.894 us; speedup vs baseline: 1.0371x; 1.0371x over previous
//
#include <hip/hip_runtime.h>
#include <hip/hip_bf16.h>
#include <math.h>

// Problem constants
#define NN 20000
#define MM 20          // neighbors (same for che and vdw)
#define EE 20          // RBF size
#define HH 128
#define BB 200
#define NCONV 3
#define CHE_CUT 8.0f
#define VDW_CUT 12.0f
#define PI_F 3.14159265358979323846f

// ---------------- activation helpers (fp32, loose 2% threshold) -------------
__device__ __forceinline__ float sp_(float x) {
    return (x > 15.f) ? x : __logf(1.f + __expf(x));
}
__device__ __forceinline__ float sig_(float x) {
    return 1.f / (1.f + __expf(-x));
}
__device__ __forceinline__ unsigned int pack_bf16x2(float lo, float hi) {
    unsigned int ul = __float_as_uint(lo), uh = __float_as_uint(hi);
    ul = (ul + 0x7fffu + ((ul >> 16) & 1u)) >> 16;          // RNE bf16
    uh = (uh + 0x7fffu + ((uh >> 16) & 1u)) >> 16;
    return ul | (uh << 16);
}

// ---------------- prep: Wc = fW @ gW_edge, bc = gb + fb @ gW_edge -----------
__global__ void prep_wc(const float* __restrict__ cfW, const float* __restrict__ cfb,
                        const float* __restrict__ cgW, const float* __restrict__ cgb,
                        const float* __restrict__ vfW, const float* __restrict__ vfb,
                        const float* __restrict__ vgW, const float* __restrict__ vgb,
                        float* __restrict__ wc, float* __restrict__ bc) {
    int e = blockIdx.x;          // 0..EE (EE == bias slot)
    int half = blockIdx.y;       // 0=che 1=vdw
    int l = blockIdx.z;
    int j = threadIdx.x;         // 0..255
    const float* fW = half ? vfW : cfW;
    const float* fb = half ? vfb : cfb;
    const float* gW = half ? vgW : cgW;
    const float* gb = half ? vgb : cgb;
    const float* gWe = gW + ((size_t)l * 384 + 128) * 256;  // edge rows 128..255
    if (e < EE) {
        const float* frow = fW + ((size_t)l * EE + e) * HH;
        float acc = 0.f;
        for (int k = 0; k < HH; ++k) acc = fmaf(frow[k], gWe[k * 256 + j], acc);
        wc[(((size_t)l * 2 + half) * EE + e) * 256 + j] = acc;
    } else {
        const float* brow = fb + (size_t)l * HH;
        float acc = gb[(size_t)l * 256 + j];
        for (int k = 0; k < HH; ++k) acc = fmaf(brow[k], gWe[k * 256 + j], acc);
        bc[((size_t)l * 2 + half) * 256 + j] = acc;
    }
}

// ---------------- prep: Wbig [NCONV][128][1024] -----------------------------
// new column order:
//   c in [  0,256): che self  (gW_self col c)           -> S cols 0..255
//   c in [256,512): vdw self  (gW_self col c-256)       -> S cols 256..511
//   c in [512,768): che nbr pairs: t=(c-512)>>1, gate=(c-512)&1 -> gW_nbr col gate*128+t
//   c in [768,1024): vdw nbr pairs likewise
__global__ void prep_wbig(const float* __restrict__ cgW, const float* __restrict__ vgW,
                          float* __restrict__ wbig) {
    int i = blockIdx.x * 256 + threadIdx.x;
    if (i >= NCONV * 128 * 1024) return;
    int l = i >> 17;
    int rem = i & 131071;
    int k = rem >> 10;         // 0..127
    int c = rem & 1023;
    float val;
    if (c < 512) {
        int half = c >> 8;
        int gcol = c & 255;
        const float* src = half ? vgW : cgW;
        val = src[((size_t)l * 384 + k) * 256 + gcol];
    } else {
        int cc = c - 512;
        int half = cc >> 8;
        int p = cc & 255;
        int gcol = (p & 1) * 128 + (p >> 1);
        const float* src = half ? vgW : cgW;
        val = src[((size_t)l * 384 + 256 + k) * 256 + gcol];
    }
    wbig[i] = val;
}

// ---------------- embed: nodes0 = atoms_embed @ emb_W + emb_b ---------------
__global__ void embed_kernel(const float* __restrict__ atoms, const float* __restrict__ W,
                             const float* __restrict__ bias, float* __restrict__ nodes) {
    int n = blockIdx.x, t = threadIdx.x;
    const float* arow = atoms + (size_t)n * 13;
    float acc = bias[t];
    #pragma unroll
    for (int k = 0; k < 13; ++k) acc = fmaf(arow[k], W[k * HH + t], acc);
    nodes[(size_t)n * HH + t] = acc;
}

// ---------------- rbf: sinc basis * cosine envelope -------------------------
__global__ void rbf_kernel(const float* __restrict__ fea, float* __restrict__ rbf,
                           int total, float cutoff) {
    int i = blockIdx.x * blockDim.x + threadIdx.x;
    if (i >= total) return;
    float d = fea[i];
    float x = d * (PI_F / cutoff);
    float s1 = sinf(x), c1 = cosf(x);
    float env = 0.5f * (c1 + 1.f);
    float scale = (d < cutoff) ? (env / d) : 0.f;
    float out[EE];
    float skm1 = 0.f, sk = s1;
    #pragma unroll
    for (int e = 0; e < EE; ++e) {
        out[e] = sk * scale;
        float nx = 2.f * c1 * sk - skm1;
        skm1 = sk; sk = nx;
    }
    float4* dst = (float4*)(rbf + (size_t)i * EE);
    #pragma unroll
    for (int q = 0; q < 5; ++q) dst[q] = ((const float4*)out)[q];
}

// ---------------- SY GEMM: [N,128] @ [128,1024] -> S fp32 + Ypk bf16x2 ------
__global__ void gemm_sy(const float* __restrict__ A, const float* __restrict__ B,
                        float* __restrict__ S, unsigned int* __restrict__ Ypk, int M) {
    __shared__ float As[32][68];
    __shared__ float Bs[32][64];
    int bm = blockIdx.y * 64;
    int bn = blockIdx.x * 64;
    int tid = threadIdx.x;
    int tx = tid & 15, ty = tid >> 4;
    float acc[4][4] = {};
    for (int kc = 0; kc < 128; kc += 32) {
        {
            int k = tid & 31, r0 = tid >> 5;
            #pragma unroll
            for (int rr = 0; rr < 8; ++rr) {
                int r = r0 + rr * 8;
                int row = bm + r; if (row >= M) row = M - 1;
                As[k][r] = A[(size_t)row * 128 + kc + k];
            }
            int c = tid & 63, k0 = tid >> 6;
            #pragma unroll
            for (int kk = 0; kk < 8; ++kk) {
                int k2 = k0 + kk * 4;
                Bs[k2][c] = B[(size_t)(kc + k2) * 1024 + bn + c];
            }
        }
        __syncthreads();
        #pragma unroll
        for (int k = 0; k < 32; ++k) {
            float4 av = *(const float4*)&As[k][ty * 4];
            float4 bv = *(const float4*)&Bs[k][tx * 4];
            float a_[4] = {av.x, av.y, av.z, av.w};
            float b_[4] = {bv.x, bv.y, bv.z, bv.w};
            #pragma unroll
            for (int i = 0; i < 4; ++i)
                #pragma unroll
                for (int j = 0; j < 4; ++j)
                    acc[i][j] = fmaf(a_[i], b_[j], acc[i][j]);
        }
        __syncthreads();
    }
    if (bn < 512) {
        #pragma unroll
        for (int i = 0; i < 4; ++i) {
            int row = bm + ty * 4 + i;
            if (row < M)
                #pragma unroll
                for (int j = 0; j < 4; ++j)
                    S[(size_t)row * 512 + bn + tx * 4 + j] = acc[i][j];
        }
    } else {
        int wbase = (bn - 512 + tx * 4) >> 1;   // word index, even -> 8B aligned
        #pragma unroll
        for (int i = 0; i < 4; ++i) {
            int row = bm + ty * 4 + i;
            if (row < M) {
                uint2 v;
                v.x = pack_bf16x2(acc[i][0], acc[i][1]);
                v.y = pack_bf16x2(acc[i][2], acc[i][3]);
                *(uint2*)(Ypk + (size_t)row * 256 + wbase) = v;
            }
        }
    }
}

// ---------------- fused edge + gate + node update ---------------------------
// S  [N][512]: che_filt | che_core | vdw_filt | vdw_core   (fp32, per-node)
// Ypk[N][256]: word t = che (filt,core) bf16x2; word 128+t = vdw pair
#define NODES_SEQ 8
__global__ void edge_kernel(const float* __restrict__ nodes_in, float* __restrict__ nodes_out,
                            const float* __restrict__ S, const unsigned int* __restrict__ Ypk,
                            const float* __restrict__ rbf_che, const float* __restrict__ rbf_vdw,
                            const int* __restrict__ idx_che, const int* __restrict__ idx_vdw,
                            const float* __restrict__ Wc,   // [2][EE][256] this layer
                            const float* __restrict__ bC) { // [2][256]
    int t = threadIdx.x;
    float wcf[EE], wcc[EE], wvf[EE], wvc[EE];
    #pragma unroll
    for (int e = 0; e < EE; ++e) {
        wcf[e] = Wc[e * 256 + t];
        wcc[e] = Wc[e * 256 + 128 + t];
        wvf[e] = Wc[EE * 256 + e * 256 + t];
        wvc[e] = Wc[EE * 256 + e * 256 + 128 + t];
    }
    float bcf = bC[t], bcc = bC[128 + t], bvf = bC[256 + t], bvc = bC[384 + t];

    for (int s = 0; s < NODES_SEQ; ++s) {
        int n = blockIdx.x * NODES_SEQ + s;
        const float* srow = S + (size_t)n * 512;
        float sCf = srow[t] + bcf,       sCc = srow[128 + t] + bcc;
        float sVf = srow[256 + t] + bvf, sVc = srow[384 + t] + bvc;
        const int* ic = idx_che + (size_t)n * MM;
        const int* iv = idx_vdw + (size_t)n * MM;
        const float* rc = rbf_che + (size_t)n * MM * EE;
        const float* rv = rbf_vdw + (size_t)n * MM * EE;
        float acc = 0.f;

        unsigned int w = Ypk[(size_t)ic[0] * 256 + t];   // prefetch edge 0
        for (int m = 0; m < MM; ++m) {
            unsigned int wn = (m + 1 < MM) ? Ypk[(size_t)ic[m + 1] * 256 + t]
                                           : Ypk[(size_t)iv[0] * 256 + 128 + t];
            float yf = __uint_as_float(w << 16);
            float yc = __uint_as_float(w & 0xffff0000u);
            float gf = sCf + yf, gc = sCc + yc;
            const float* r = rc + m * EE;
            #pragma unroll
            for (int e = 0; e < EE; ++e) {
                gf = fmaf(r[e], wcf[e], gf);
                gc = fmaf(r[e], wcc[e], gc);
            }
            acc += sig_(gf) * sp_(gc);
            w = wn;
        }
        for (int m = 0; m < MM; ++m) {
            unsigned int wn = (m + 1 < MM) ? Ypk[(size_t)iv[m + 1] * 256 + 128 + t] : 0u;
            float yf = __uint_as_float(w << 16);
            float yc = __uint_as_float(w & 0xffff0000u);
            float gf = sVf + yf, gc = sVc + yc;
            const float* r = rv + m * EE;
            #pragma unroll
            for (int e = 0; e < EE; ++e) {
                gf = fmaf(r[e], wvf[e], gf);
                gc = fmaf(r[e], wvc[e], gc);
            }
            acc += sig_(gf) * sp_(gc);
            w = wn;
        }
        float old = nodes_in[(size_t)n * HH + t];
        nodes_out[(size_t)n * HH + t] = sp_(old + acc);
    }
}

// ---------------- pooling + head MLP ---------------------------------------
__global__ void pool_kernel(const float* __restrict__ nodes, const int* __restrict__ num_atoms,
                            const float* __restrict__ fc1_W, const float* __restrict__ fc1_b,
                            const float* __restrict__ out_W, const float* __restrict__ out_b,
                            float* __restrict__ out) {
    __shared__ float sh[HH];
    __shared__ float red[HH];
    int b = blockIdx.x, t = threadIdx.x;
    int start = 0;
    for (int i = 0; i < b; ++i) start += num_atoms[i];
    int cnt = num_atoms[b];
    float sum = 0.f;
    for (int a = 0; a < cnt; ++a) sum += nodes[(size_t)(start + a) * HH + t];
    float mean = sum / (float)cnt;
    sh[t] = sp_(mean);
    __syncthreads();
    float o = fc1_b[t];
    #pragma unroll 4
    for (int k = 0; k < HH; ++k) o = fmaf(sh[k], fc1_W[k * HH + t], o);
    red[t] = sp_(o) * out_W[t];
    __syncthreads();
    if (t == 0) {
        float tot = 0.f;
        for (int k = 0; k < HH; ++k) tot += red[k];
        out[b] = tot + out_b[0];
    }
}

// ---------------- launch ----------------------------------------------------
extern "C" void kernel_launch(void* const* d_in, const int* in_sizes, int n_in,
                              void* d_out, int out_size, void* d_ws, size_t ws_size,
                              hipStream_t stream) {
    const float* atoms_embed   = (const float*)d_in[0];
    const float* che_nbrs_fea  = (const float*)d_in[1];
    const float* vdw_nbrs_fea  = (const float*)d_in[2];
    const int*   che_nbrs_idx  = (const int*)  d_in[3];
    const int*   vdw_nbrs_idx  = (const int*)  d_in[4];
    const int*   num_atoms     = (const int*)  d_in[5];
    const float* emb_W         = (const float*)d_in[6];
    const float* emb_b         = (const float*)d_in[7];
    const float* che_filter_W  = (const float*)d_in[8];
    const float* che_filter_b  = (const float*)d_in[9];
    const float* che_fc_W      = (const float*)d_in[10];
    const float* che_fc_b      = (const float*)d_in[11];
    const float* vdw_filter_W  = (const float*)d_in[12];
    const float* vdw_filter_b  = (const float*)d_in[13];
    const float* vdw_fc_W      = (const float*)d_in[14];
    const float* vdw_fc_b      = (const float*)d_in[15];
    const float* fc1_W         = (const float*)d_in[16];
    const float* fc1_b         = (const float*)d_in[17];
    const float* out_W         = (const float*)d_in[18];
    const float* out_b         = (const float*)d_in[19];
    float* out = (float*)d_out;

    // workspace layout (floats), ~148 MB
    float* w = (float*)d_ws;
    float* nodesA  = w;                                    // 2.56M
    float* nodesB  = nodesA + (size_t)NN * HH;             // 2.56M
    float* S       = nodesB + (size_t)NN * HH;             // 10.24M
    unsigned int* Ypk = (unsigned int*)(S + (size_t)NN * 512); // 5.12M words
    float* rbf_che = (float*)(Ypk + (size_t)NN * 256);     // 8M
    float* rbf_vdw = rbf_che + (size_t)NN * MM * EE;       // 8M
    float* wbig    = rbf_vdw + (size_t)NN * MM * EE;       // 393K
    float* wc      = wbig + (size_t)NCONV * 128 * 1024;    // 30.7K
    float* bc      = wc + (size_t)NCONV * 2 * EE * 256;    // 1.5K

    prep_wc<<<dim3(EE + 1, 2, NCONV), 256, 0, stream>>>(
        che_filter_W, che_filter_b, che_fc_W, che_fc_b,
        vdw_filter_W, vdw_filter_b, vdw_fc_W, vdw_fc_b, wc, bc);
    prep_wbig<<<(NCONV * 128 * 1024 + 255) / 256, 256, 0, stream>>>(che_fc_W, vdw_fc_W, wbig);
    embed_kernel<<<NN, HH, 0, stream>>>(atoms_embed, emb_W, emb_b, nodesA);
    rbf_kernel<<<(NN * MM + 255) / 256, 256, 0, stream>>>(che_nbrs_fea, rbf_che, NN * MM, CHE_CUT);
    rbf_kernel<<<(NN * MM + 255) / 256, 256, 0, stream>>>(vdw_nbrs_fea, rbf_vdw, NN * MM, VDW_CUT);

    float* cur = nodesA;
    float* nxt = nodesB;
    for (int l = 0; l < NCONV; ++l) {
        gemm_sy<<<dim3(16, (NN + 63) / 64), 256, 0, stream>>>(cur, wbig + (size_t)l * 128 * 1024, S, Ypk, NN);
        edge_kernel<<<NN / NODES_SEQ, HH, 0, stream>>>(
            cur, nxt, S, Ypk, rbf_che, rbf_vdw, che_nbrs_idx, vdw_nbrs_idx,
            wc + (size_t)l * 2 * EE * 256, bc + (size_t)l * 2 * 256);
        float* tmp = cur; cur = nxt; nxt = tmp;
    }

    pool_kernel<<<BB, HH, 0, stream>>>(cur, num_atoms, fc1_W, fc1_b, out_W, out_b, out);
}

// Round 4
// 1100.934 us; speedup vs baseline: 1.2377x; 1.1934x over previous
//
#include <hip/hip_runtime.h>
#include <hip/hip_bf16.h>
#include <math.h>

// Problem constants
#define NN 20000
#define MM 20          // neighbors (same for che and vdw)
#define EE 20          // RBF size
#define E2 10          // EE/2 packed pairs
#define HH 128
#define BB 200
#define NCONV 3
#define CHE_CUT 8.0f
#define VDW_CUT 12.0f
#define PI_F 3.14159265358979323846f

// NOTE: __builtin_amdgcn_cvt_pkrtz / __builtin_amdgcn_fdot2 use __fp16 vectors
typedef __fp16 half2_t __attribute__((ext_vector_type(2)));

// ---------------- helpers ---------------------------------------------------
__device__ __forceinline__ float sp_(float x) {
    return (x > 15.f) ? x : __logf(1.f + __expf(x));
}
__device__ __forceinline__ float sig_(float x) {
    return 1.f / (1.f + __expf(-x));
}
__device__ __forceinline__ float fdot2_(half2_t a, half2_t b, float c) {
#if __has_builtin(__builtin_amdgcn_fdot2)
    return __builtin_amdgcn_fdot2(a, b, c, false);
#else
    return (float)a.x * (float)b.x + (float)a.y * (float)b.y + c;
#endif
}

// ---------------- prep: Wc = fW @ gW_edge (packed f16x2 pairs over E) -------
// wcpk layout: [l][half][e2][gate][128]  (gate 0=filt, 1=core)
// bc   layout: [l][half][256] fp32 (gb + fb @ gW_edge)
__global__ void prep_wc(const float* __restrict__ cfW, const float* __restrict__ cfb,
                        const float* __restrict__ cgW, const float* __restrict__ cgb,
                        const float* __restrict__ vfW, const float* __restrict__ vfb,
                        const float* __restrict__ vgW, const float* __restrict__ vgb,
                        half2_t* __restrict__ wcpk, float* __restrict__ bc) {
    int e2 = blockIdx.x;         // 0..E2 (E2 == bias slot)
    int half = blockIdx.y;       // 0=che 1=vdw
    int l = blockIdx.z;
    int j = threadIdx.x;         // 0..255 (= gate*128 + t)
    const float* fW = half ? vfW : cfW;
    const float* fb = half ? vfb : cfb;
    const float* gW = half ? vgW : cgW;
    const float* gb = half ? vgb : cgb;
    const float* gWe = gW + ((size_t)l * 384 + 128) * 256;  // edge rows 128..255
    if (e2 < E2) {
        const float* r0 = fW + ((size_t)l * EE + 2 * e2) * HH;
        const float* r1 = r0 + HH;
        float a0 = 0.f, a1 = 0.f;
        for (int k = 0; k < HH; ++k) {
            float g = gWe[k * 256 + j];
            a0 = fmaf(r0[k], g, a0);
            a1 = fmaf(r1[k], g, a1);
        }
        half2_t p = __builtin_amdgcn_cvt_pkrtz(a0, a1);
        int gate = j >> 7, t = j & 127;
        wcpk[(((size_t)(l * 2 + half) * E2 + e2) * 2 + gate) * 128 + t] = p;
    } else {
        const float* brow = fb + (size_t)l * HH;
        float acc = gb[(size_t)l * 256 + j];
        for (int k = 0; k < HH; ++k) acc = fmaf(brow[k], gWe[k * 256 + j], acc);
        bc[((size_t)l * 2 + half) * 256 + j] = acc;
    }
}

// ---------------- prep: Wbig [NCONV][128][1024] -----------------------------
// column order:
//   c in [  0,256): che self  (gW_self col c)
//   c in [256,512): vdw self  (gW_self col c-256)
//   c in [512,768): che nbr pairs: t=(c-512)>>1, gate=(c-512)&1 -> gW_nbr col gate*128+t
//   c in [768,1024): vdw nbr pairs likewise
__global__ void prep_wbig(const float* __restrict__ cgW, const float* __restrict__ vgW,
                          float* __restrict__ wbig) {
    int i = blockIdx.x * 256 + threadIdx.x;
    if (i >= NCONV * 128 * 1024) return;
    int l = i >> 17;
    int rem = i & 131071;
    int k = rem >> 10;
    int c = rem & 1023;
    float val;
    if (c < 512) {
        int half = c >> 8;
        int gcol = c & 255;
        const float* src = half ? vgW : cgW;
        val = src[((size_t)l * 384 + k) * 256 + gcol];
    } else {
        int cc = c - 512;
        int half = cc >> 8;
        int p = cc & 255;
        int gcol = (p & 1) * 128 + (p >> 1);
        const float* src = half ? vgW : cgW;
        val = src[((size_t)l * 384 + 256 + k) * 256 + gcol];
    }
    wbig[i] = val;
}

// ---------------- embed -----------------------------------------------------
__global__ void embed_kernel(const float* __restrict__ atoms, const float* __restrict__ W,
                             const float* __restrict__ bias, float* __restrict__ nodes) {
    int n = blockIdx.x, t = threadIdx.x;
    const float* arow = atoms + (size_t)n * 13;
    float acc = bias[t];
    #pragma unroll
    for (int k = 0; k < 13; ++k) acc = fmaf(arow[k], W[k * HH + t], acc);
    nodes[(size_t)n * HH + t] = acc;
}

// ---------------- rbf: packed f16x2 pairs -----------------------------------
__global__ void rbf_kernel(const float* __restrict__ fea, half2_t* __restrict__ rpk,
                           int total, float cutoff) {
    int i = blockIdx.x * blockDim.x + threadIdx.x;
    if (i >= total) return;
    float d = fea[i];
    float x = d * (PI_F / cutoff);
    float s1 = sinf(x), c1 = cosf(x);
    float env = 0.5f * (c1 + 1.f);
    float scale = (d < cutoff) ? (env / d) : 0.f;
    float out[EE];
    float skm1 = 0.f, sk = s1;
    #pragma unroll
    for (int e = 0; e < EE; ++e) {
        out[e] = sk * scale;
        float nx = 2.f * c1 * sk - skm1;
        skm1 = sk; sk = nx;
    }
    half2_t* dst = rpk + (size_t)i * E2;
    #pragma unroll
    for (int e = 0; e < E2; ++e)
        dst[e] = __builtin_amdgcn_cvt_pkrtz(out[2 * e], out[2 * e + 1]);
}

// ---------------- SY GEMM: [N,128] @ [128,1024] -> S fp32 + Ypk f16x2 -------
__global__ void gemm_sy(const float* __restrict__ A, const float* __restrict__ B,
                        float* __restrict__ S, half2_t* __restrict__ Ypk, int M) {
    __shared__ float As[32][68];
    __shared__ float Bs[32][64];
    int bm = blockIdx.y * 64;
    int bn = blockIdx.x * 64;
    int tid = threadIdx.x;
    int tx = tid & 15, ty = tid >> 4;
    float acc[4][4] = {};
    for (int kc = 0; kc < 128; kc += 32) {
        {
            int k = tid & 31, r0 = tid >> 5;
            #pragma unroll
            for (int rr = 0; rr < 8; ++rr) {
                int r = r0 + rr * 8;
                int row = bm + r; if (row >= M) row = M - 1;
                As[k][r] = A[(size_t)row * 128 + kc + k];
            }
            int c = tid & 63, k0 = tid >> 6;
            #pragma unroll
            for (int kk = 0; kk < 8; ++kk) {
                int k2 = k0 + kk * 4;
                Bs[k2][c] = B[(size_t)(kc + k2) * 1024 + bn + c];
            }
        }
        __syncthreads();
        #pragma unroll
        for (int k = 0; k < 32; ++k) {
            float4 av = *(const float4*)&As[k][ty * 4];
            float4 bv = *(const float4*)&Bs[k][tx * 4];
            float a_[4] = {av.x, av.y, av.z, av.w};
            float b_[4] = {bv.x, bv.y, bv.z, bv.w};
            #pragma unroll
            for (int i = 0; i < 4; ++i)
                #pragma unroll
                for (int j = 0; j < 4; ++j)
                    acc[i][j] = fmaf(a_[i], b_[j], acc[i][j]);
        }
        __syncthreads();
    }
    if (bn < 512) {
        #pragma unroll
        for (int i = 0; i < 4; ++i) {
            int row = bm + ty * 4 + i;
            if (row < M)
                #pragma unroll
                for (int j = 0; j < 4; ++j)
                    S[(size_t)row * 512 + bn + tx * 4 + j] = acc[i][j];
        }
    } else {
        int wbase = (bn - 512 + tx * 4) >> 1;   // word index, even -> 8B aligned
        #pragma unroll
        for (int i = 0; i < 4; ++i) {
            int row = bm + ty * 4 + i;
            if (row < M) {
                half2_t p0 = __builtin_amdgcn_cvt_pkrtz(acc[i][0], acc[i][1]);
                half2_t p1 = __builtin_amdgcn_cvt_pkrtz(acc[i][2], acc[i][3]);
                half2_t* dst = Ypk + (size_t)row * 256 + wbase;
                dst[0] = p0;
                dst[1] = p1;
            }
        }
    }
}

// ---------------- fused edge + gate + node update ---------------------------
// S  [N][512]: che_filt | che_core | vdw_filt | vdw_core   (fp32, per-node)
// Ypk[N][256]: word t = che (filt,core) f16x2; word 128+t = vdw pair
#define NSEQ 8
__global__ void edge_kernel(const float* __restrict__ nodes_in, float* __restrict__ nodes_out,
                            const float* __restrict__ S, const half2_t* __restrict__ Ypk,
                            const half2_t* __restrict__ rpk_che, const half2_t* __restrict__ rpk_vdw,
                            const int* __restrict__ idx_che, const int* __restrict__ idx_vdw,
                            const half2_t* __restrict__ Wcpk,  // [2][E2][2][128] this layer
                            const float* __restrict__ bC) {    // [2][256]
    int t = threadIdx.x;
    half2_t wcf[E2], wcc[E2], wvf[E2], wvc[E2];
    #pragma unroll
    for (int e = 0; e < E2; ++e) {
        wcf[e] = Wcpk[((size_t)e * 2 + 0) * 128 + t];
        wcc[e] = Wcpk[((size_t)e * 2 + 1) * 128 + t];
        wvf[e] = Wcpk[((size_t)(E2 + e) * 2 + 0) * 128 + t];
        wvc[e] = Wcpk[((size_t)(E2 + e) * 2 + 1) * 128 + t];
    }
    float bcf = bC[t], bcc = bC[128 + t], bvf = bC[256 + t], bvc = bC[384 + t];

    for (int s = 0; s < NSEQ; ++s) {
        int n = blockIdx.x * NSEQ + s;
        const int* ic = idx_che + (size_t)n * MM;
        const int* iv = idx_vdw + (size_t)n * MM;
        // batch all 40 gather loads -> deep vmcnt pipeline
        half2_t yw[2 * MM];
        #pragma unroll
        for (int m = 0; m < MM; ++m) yw[m] = Ypk[(size_t)ic[m] * 256 + t];
        #pragma unroll
        for (int m = 0; m < MM; ++m) yw[MM + m] = Ypk[(size_t)iv[m] * 256 + 128 + t];

        const float* srow = S + (size_t)n * 512;
        float sCf = srow[t] + bcf,       sCc = srow[128 + t] + bcc;
        float sVf = srow[256 + t] + bvf, sVc = srow[384 + t] + bvc;
        const half2_t* rc = rpk_che + (size_t)n * (MM * E2);
        const half2_t* rv = rpk_vdw + (size_t)n * (MM * E2);
        float acc = 0.f;

        #pragma unroll
        for (int m = 0; m < MM; ++m) {
            half2_t w = yw[m];
            float gf = sCf + (float)w.x;
            float gc = sCc + (float)w.y;
            const half2_t* r = rc + m * E2;
            #pragma unroll
            for (int e = 0; e < E2; ++e) {
                gf = fdot2_(r[e], wcf[e], gf);
                gc = fdot2_(r[e], wcc[e], gc);
            }
            acc += sig_(gf) * sp_(gc);
        }
        #pragma unroll
        for (int m = 0; m < MM; ++m) {
            half2_t w = yw[MM + m];
            float gf = sVf + (float)w.x;
            float gc = sVc + (float)w.y;
            const half2_t* r = rv + m * E2;
            #pragma unroll
            for (int e = 0; e < E2; ++e) {
                gf = fdot2_(r[e], wvf[e], gf);
                gc = fdot2_(r[e], wvc[e], gc);
            }
            acc += sig_(gf) * sp_(gc);
        }
        float old = nodes_in[(size_t)n * HH + t];
        nodes_out[(size_t)n * HH + t] = sp_(old + acc);
    }
}

// ---------------- pooling + head MLP ---------------------------------------
__global__ void pool_kernel(const float* __restrict__ nodes, const int* __restrict__ num_atoms,
                            const float* __restrict__ fc1_W, const float* __restrict__ fc1_b,
                            const float* __restrict__ out_W, const float* __restrict__ out_b,
                            float* __restrict__ out) {
    __shared__ float sh[HH];
    __shared__ float red[HH];
    int b = blockIdx.x, t = threadIdx.x;
    int start = 0;
    for (int i = 0; i < b; ++i) start += num_atoms[i];
    int cnt = num_atoms[b];
    float sum = 0.f;
    for (int a = 0; a < cnt; ++a) sum += nodes[(size_t)(start + a) * HH + t];
    float mean = sum / (float)cnt;
    sh[t] = sp_(mean);
    __syncthreads();
    float o = fc1_b[t];
    #pragma unroll 4
    for (int k = 0; k < HH; ++k) o = fmaf(sh[k], fc1_W[k * HH + t], o);
    red[t] = sp_(o) * out_W[t];
    __syncthreads();
    if (t == 0) {
        float tot = 0.f;
        for (int k = 0; k < HH; ++k) tot += red[k];
        out[b] = tot + out_b[0];
    }
}

// ---------------- launch ----------------------------------------------------
extern "C" void kernel_launch(void* const* d_in, const int* in_sizes, int n_in,
                              void* d_out, int out_size, void* d_ws, size_t ws_size,
                              hipStream_t stream) {
    const float* atoms_embed   = (const float*)d_in[0];
    const float* che_nbrs_fea  = (const float*)d_in[1];
    const float* vdw_nbrs_fea  = (const float*)d_in[2];
    const int*   che_nbrs_idx  = (const int*)  d_in[3];
    const int*   vdw_nbrs_idx  = (const int*)  d_in[4];
    const int*   num_atoms     = (const int*)  d_in[5];
    const float* emb_W         = (const float*)d_in[6];
    const float* emb_b         = (const float*)d_in[7];
    const float* che_filter_W  = (const float*)d_in[8];
    const float* che_filter_b  = (const float*)d_in[9];
    const float* che_fc_W      = (const float*)d_in[10];
    const float* che_fc_b      = (const float*)d_in[11];
    const float* vdw_filter_W  = (const float*)d_in[12];
    const float* vdw_filter_b  = (const float*)d_in[13];
    const float* vdw_fc_W      = (const float*)d_in[14];
    const float* vdw_fc_b      = (const float*)d_in[15];
    const float* fc1_W         = (const float*)d_in[16];
    const float* fc1_b         = (const float*)d_in[17];
    const float* out_W         = (const float*)d_in[18];
    const float* out_b         = (const float*)d_in[19];
    float* out = (float*)d_out;

    // workspace layout, ~116 MB
    float* w = (float*)d_ws;
    float* nodesA  = w;                                    // 2.56M f32
    float* nodesB  = nodesA + (size_t)NN * HH;             // 2.56M f32
    float* S       = nodesB + (size_t)NN * HH;             // 10.24M f32
    half2_t* Ypk   = (half2_t*)(S + (size_t)NN * 512);     // 5.12M words
    half2_t* rpk_che = Ypk + (size_t)NN * 256;             // 4M words
    half2_t* rpk_vdw = rpk_che + (size_t)NN * MM * E2;     // 4M words
    float* wbig    = (float*)(rpk_vdw + (size_t)NN * MM * E2); // 393K f32
    half2_t* wcpk  = (half2_t*)(wbig + (size_t)NCONV * 128 * 1024); // 15360 words
    float* bc      = (float*)(wcpk + (size_t)NCONV * 2 * E2 * 2 * 128); // 1536 f32

    prep_wc<<<dim3(E2 + 1, 2, NCONV), 256, 0, stream>>>(
        che_filter_W, che_filter_b, che_fc_W, che_fc_b,
        vdw_filter_W, vdw_filter_b, vdw_fc_W, vdw_fc_b, wcpk, bc);
    prep_wbig<<<(NCONV * 128 * 1024 + 255) / 256, 256, 0, stream>>>(che_fc_W, vdw_fc_W, wbig);
    embed_kernel<<<NN, HH, 0, stream>>>(atoms_embed, emb_W, emb_b, nodesA);
    rbf_kernel<<<(NN * MM + 255) / 256, 256, 0, stream>>>(che_nbrs_fea, rpk_che, NN * MM, CHE_CUT);
    rbf_kernel<<<(NN * MM + 255) / 256, 256, 0, stream>>>(vdw_nbrs_fea, rpk_vdw, NN * MM, VDW_CUT);

    float* cur = nodesA;
    float* nxt = nodesB;
    for (int l = 0; l < NCONV; ++l) {
        gemm_sy<<<dim3(16, (NN + 63) / 64), 256, 0, stream>>>(cur, wbig + (size_t)l * 128 * 1024, S, Ypk, NN);
        edge_kernel<<<NN / NSEQ, HH, 0, stream>>>(
            cur, nxt, S, Ypk, rpk_che, rpk_vdw, che_nbrs_idx, vdw_nbrs_idx,
            wcpk + (size_t)l * 2 * E2 * 2 * 128, bc + (size_t)l * 2 * 256);
        float* tmp = cur; cur = nxt; nxt = tmp;
    }

    pool_kernel<<<BB, HH, 0, stream>>>(cur, num_atoms, fc1_W, fc1_b, out_W, out_b, out);
}

// Round 5
// 893.430 us; speedup vs baseline: 1.5252x; 1.2323x over previous
//
#include <hip/hip_runtime.h>
#include <hip/hip_bf16.h>
#include <math.h>

// Problem constants
#define NN 20000
#define MM 20          // neighbors (same for che and vdw)
#define EE 20          // RBF size
#define E2 10          // EE/2 packed pairs
#define HH 128
#define BB 200
#define NCONV 3
#define CHE_CUT 8.0f
#define VDW_CUT 12.0f
#define PI_F 3.14159265358979323846f

// NOTE: __builtin_amdgcn_cvt_pkrtz / __builtin_amdgcn_fdot2 use __fp16 vectors
typedef __fp16 half2_t __attribute__((ext_vector_type(2)));

// ---------------- helpers ---------------------------------------------------
__device__ __forceinline__ float sp_(float x) {
    return (x > 15.f) ? x : __logf(1.f + __expf(x));
}
__device__ __forceinline__ float sig_(float x) {
    return 1.f / (1.f + __expf(-x));
}
__device__ __forceinline__ float fdot2_(half2_t a, half2_t b, float c) {
#if __has_builtin(__builtin_amdgcn_fdot2)
    return __builtin_amdgcn_fdot2(a, b, c, false);
#else
    return (float)a.x * (float)b.x + (float)a.y * (float)b.y + c;
#endif
}

// ---------------- prep: Wc = fW @ gW_edge (packed f16x2 pairs over E) -------
// wcpk layout: [l][half][e2][gate][128]  (gate 0=filt, 1=core)
// bc   layout: [l][half][256] fp32 (gb + fb @ gW_edge)
__global__ void prep_wc(const float* __restrict__ cfW, const float* __restrict__ cfb,
                        const float* __restrict__ cgW, const float* __restrict__ cgb,
                        const float* __restrict__ vfW, const float* __restrict__ vfb,
                        const float* __restrict__ vgW, const float* __restrict__ vgb,
                        half2_t* __restrict__ wcpk, float* __restrict__ bc) {
    int e2 = blockIdx.x;         // 0..E2 (E2 == bias slot)
    int half = blockIdx.y;       // 0=che 1=vdw
    int l = blockIdx.z;
    int j = threadIdx.x;         // 0..255 (= gate*128 + t)
    const float* fW = half ? vfW : cfW;
    const float* fb = half ? vfb : cfb;
    const float* gW = half ? vgW : cgW;
    const float* gb = half ? vgb : cgb;
    const float* gWe = gW + ((size_t)l * 384 + 128) * 256;  // edge rows 128..255
    if (e2 < E2) {
        const float* r0 = fW + ((size_t)l * EE + 2 * e2) * HH;
        const float* r1 = r0 + HH;
        float a0 = 0.f, a1 = 0.f;
        for (int k = 0; k < HH; ++k) {
            float g = gWe[k * 256 + j];
            a0 = fmaf(r0[k], g, a0);
            a1 = fmaf(r1[k], g, a1);
        }
        half2_t p = __builtin_amdgcn_cvt_pkrtz(a0, a1);
        int gate = j >> 7, t = j & 127;
        wcpk[(((size_t)(l * 2 + half) * E2 + e2) * 2 + gate) * 128 + t] = p;
    } else {
        const float* brow = fb + (size_t)l * HH;
        float acc = gb[(size_t)l * 256 + j];
        for (int k = 0; k < HH; ++k) acc = fmaf(brow[k], gWe[k * 256 + j], acc);
        bc[((size_t)l * 2 + half) * 256 + j] = acc;
    }
}

// ---------------- prep: Wbig [NCONV][128][1024] -----------------------------
__global__ void prep_wbig(const float* __restrict__ cgW, const float* __restrict__ vgW,
                          float* __restrict__ wbig) {
    int i = blockIdx.x * 256 + threadIdx.x;
    if (i >= NCONV * 128 * 1024) return;
    int l = i >> 17;
    int rem = i & 131071;
    int k = rem >> 10;
    int c = rem & 1023;
    float val;
    if (c < 512) {
        int half = c >> 8;
        int gcol = c & 255;
        const float* src = half ? vgW : cgW;
        val = src[((size_t)l * 384 + k) * 256 + gcol];
    } else {
        int cc = c - 512;
        int half = cc >> 8;
        int p = cc & 255;
        int gcol = (p & 1) * 128 + (p >> 1);
        const float* src = half ? vgW : cgW;
        val = src[((size_t)l * 384 + 256 + k) * 256 + gcol];
    }
    wbig[i] = val;
}

// ---------------- embed -----------------------------------------------------
__global__ void embed_kernel(const float* __restrict__ atoms, const float* __restrict__ W,
                             const float* __restrict__ bias, float* __restrict__ nodes) {
    int n = blockIdx.x, t = threadIdx.x;
    const float* arow = atoms + (size_t)n * 13;
    float acc = bias[t];
    #pragma unroll
    for (int k = 0; k < 13; ++k) acc = fmaf(arow[k], W[k * HH + t], acc);
    nodes[(size_t)n * HH + t] = acc;
}

// ---------------- rbf: packed f16x2 pairs -----------------------------------
__global__ void rbf_kernel(const float* __restrict__ fea, half2_t* __restrict__ rpk,
                           int total, float cutoff) {
    int i = blockIdx.x * blockDim.x + threadIdx.x;
    if (i >= total) return;
    float d = fea[i];
    float x = d * (PI_F / cutoff);
    float s1 = sinf(x), c1 = cosf(x);
    float env = 0.5f * (c1 + 1.f);
    float scale = (d < cutoff) ? (env / d) : 0.f;
    float out[EE];
    float skm1 = 0.f, sk = s1;
    #pragma unroll
    for (int e = 0; e < EE; ++e) {
        out[e] = sk * scale;
        float nx = 2.f * c1 * sk - skm1;
        skm1 = sk; sk = nx;
    }
    half2_t* dst = rpk + (size_t)i * E2;
    #pragma unroll
    for (int e = 0; e < E2; ++e)
        dst[e] = __builtin_amdgcn_cvt_pkrtz(out[2 * e], out[2 * e + 1]);
}

// ---------------- SY GEMM: [N,128] @ [128,1024] -> S fp32 + Ypk f16x2 -------
__global__ void gemm_sy(const float* __restrict__ A, const float* __restrict__ B,
                        float* __restrict__ S, half2_t* __restrict__ Ypk, int M) {
    __shared__ float As[32][68];
    __shared__ float Bs[32][64];
    int bm = blockIdx.y * 64;
    int bn = blockIdx.x * 64;
    int tid = threadIdx.x;
    int tx = tid & 15, ty = tid >> 4;
    float acc[4][4] = {};
    for (int kc = 0; kc < 128; kc += 32) {
        {
            int k = tid & 31, r0 = tid >> 5;
            #pragma unroll
            for (int rr = 0; rr < 8; ++rr) {
                int r = r0 + rr * 8;
                int row = bm + r; if (row >= M) row = M - 1;
                As[k][r] = A[(size_t)row * 128 + kc + k];
            }
            int c = tid & 63, k0 = tid >> 6;
            #pragma unroll
            for (int kk = 0; kk < 8; ++kk) {
                int k2 = k0 + kk * 4;
                Bs[k2][c] = B[(size_t)(kc + k2) * 1024 + bn + c];
            }
        }
        __syncthreads();
        #pragma unroll
        for (int k = 0; k < 32; ++k) {
            float4 av = *(const float4*)&As[k][ty * 4];
            float4 bv = *(const float4*)&Bs[k][tx * 4];
            float a_[4] = {av.x, av.y, av.z, av.w};
            float b_[4] = {bv.x, bv.y, bv.z, bv.w};
            #pragma unroll
            for (int i = 0; i < 4; ++i)
                #pragma unroll
                for (int j = 0; j < 4; ++j)
                    acc[i][j] = fmaf(a_[i], b_[j], acc[i][j]);
        }
        __syncthreads();
    }
    if (bn < 512) {
        #pragma unroll
        for (int i = 0; i < 4; ++i) {
            int row = bm + ty * 4 + i;
            if (row < M)
                #pragma unroll
                for (int j = 0; j < 4; ++j)
                    S[(size_t)row * 512 + bn + tx * 4 + j] = acc[i][j];
        }
    } else {
        int wbase = (bn - 512 + tx * 4) >> 1;   // word index, even -> 8B aligned
        #pragma unroll
        for (int i = 0; i < 4; ++i) {
            int row = bm + ty * 4 + i;
            if (row < M) {
                half2_t p0 = __builtin_amdgcn_cvt_pkrtz(acc[i][0], acc[i][1]);
                half2_t p1 = __builtin_amdgcn_cvt_pkrtz(acc[i][2], acc[i][3]);
                half2_t* dst = Ypk + (size_t)row * 256 + wbase;
                dst[0] = p0;
                dst[1] = p1;
            }
        }
    }
}

// ---------------- fused edge + gate + node update ---------------------------
// S  [N][512]: che_filt | che_core | vdw_filt | vdw_core   (fp32, per-node)
// Ypk[N][256]: word t = che (filt,core) f16x2; word 128+t = vdw pair
// One node per 128-thread block: straight-line code, deep gather batch.
__global__ __launch_bounds__(128)
void edge_kernel(const float* __restrict__ nodes_in, float* __restrict__ nodes_out,
                 const float* __restrict__ S, const half2_t* __restrict__ Ypk,
                 const half2_t* __restrict__ rpk_che, const half2_t* __restrict__ rpk_vdw,
                 const int* __restrict__ idx_che, const int* __restrict__ idx_vdw,
                 const half2_t* __restrict__ Wcpk,  // [2][E2][2][128] this layer
                 const float* __restrict__ bC) {    // [2][256]
    int t = threadIdx.x;
    int n = blockIdx.x;

    // ---- neighbor indices (uniform -> s_load) ----
    const int* ic = idx_che + (size_t)n * MM;
    const int* iv = idx_vdw + (size_t)n * MM;
    int jc[MM], jv[MM];
    #pragma unroll
    for (int m = 0; m < MM; ++m) jc[m] = ic[m];
    #pragma unroll
    for (int m = 0; m < MM; ++m) jv[m] = iv[m];

    // ---- batch ALL 40 gathers up front (deep vmcnt pipeline) ----
    half2_t yw[2 * MM];
    #pragma unroll
    for (int m = 0; m < MM; ++m) yw[m] = Ypk[(size_t)jc[m] * 256 + t];
    #pragma unroll
    for (int m = 0; m < MM; ++m) yw[MM + m] = Ypk[(size_t)jv[m] * 256 + 128 + t];

    // ---- per-node self terms + old value (independent loads) ----
    const float* srow = S + (size_t)n * 512;
    float sCf = srow[t],       sCc = srow[128 + t];
    float sVf = srow[256 + t], sVc = srow[384 + t];
    float old = nodes_in[(size_t)n * HH + t];

    // ---- weights (per-block reload; L1/L2-hot) ----
    half2_t wcf[E2], wcc[E2], wvf[E2], wvc[E2];
    #pragma unroll
    for (int e = 0; e < E2; ++e) {
        wcf[e] = Wcpk[((size_t)e * 2 + 0) * 128 + t];
        wcc[e] = Wcpk[((size_t)e * 2 + 1) * 128 + t];
        wvf[e] = Wcpk[((size_t)(E2 + e) * 2 + 0) * 128 + t];
        wvc[e] = Wcpk[((size_t)(E2 + e) * 2 + 1) * 128 + t];
    }
    sCf += bC[t];       sCc += bC[128 + t];
    sVf += bC[256 + t]; sVc += bC[384 + t];

    const half2_t* rc = rpk_che + (size_t)n * (MM * E2);
    const half2_t* rv = rpk_vdw + (size_t)n * (MM * E2);
    float acc = 0.f;

    #pragma unroll
    for (int m = 0; m < MM; ++m) {
        half2_t w = yw[m];
        float gf = sCf + (float)w.x;
        float gc = sCc + (float)w.y;
        const half2_t* r = rc + m * E2;
        #pragma unroll
        for (int e = 0; e < E2; ++e) {
            gf = fdot2_(r[e], wcf[e], gf);
            gc = fdot2_(r[e], wcc[e], gc);
        }
        acc += sig_(gf) * sp_(gc);
    }
    #pragma unroll
    for (int m = 0; m < MM; ++m) {
        half2_t w = yw[MM + m];
        float gf = sVf + (float)w.x;
        float gc = sVc + (float)w.y;
        const half2_t* r = rv + m * E2;
        #pragma unroll
        for (int e = 0; e < E2; ++e) {
            gf = fdot2_(r[e], wvf[e], gf);
            gc = fdot2_(r[e], wvc[e], gc);
        }
        acc += sig_(gf) * sp_(gc);
    }
    nodes_out[(size_t)n * HH + t] = sp_(old + acc);
}

// ---------------- pooling + head MLP ---------------------------------------
__global__ void pool_kernel(const float* __restrict__ nodes, const int* __restrict__ num_atoms,
                            const float* __restrict__ fc1_W, const float* __restrict__ fc1_b,
                            const float* __restrict__ out_W, const float* __restrict__ out_b,
                            float* __restrict__ out) {
    __shared__ float sh[HH];
    __shared__ float red[HH];
    int b = blockIdx.x, t = threadIdx.x;
    int start = 0;
    for (int i = 0; i < b; ++i) start += num_atoms[i];
    int cnt = num_atoms[b];
    float sum = 0.f;
    for (int a = 0; a < cnt; ++a) sum += nodes[(size_t)(start + a) * HH + t];
    float mean = sum / (float)cnt;
    sh[t] = sp_(mean);
    __syncthreads();
    float o = fc1_b[t];
    #pragma unroll 4
    for (int k = 0; k < HH; ++k) o = fmaf(sh[k], fc1_W[k * HH + t], o);
    red[t] = sp_(o) * out_W[t];
    __syncthreads();
    if (t == 0) {
        float tot = 0.f;
        for (int k = 0; k < HH; ++k) tot += red[k];
        out[b] = tot + out_b[0];
    }
}

// ---------------- launch ----------------------------------------------------
extern "C" void kernel_launch(void* const* d_in, const int* in_sizes, int n_in,
                              void* d_out, int out_size, void* d_ws, size_t ws_size,
                              hipStream_t stream) {
    const float* atoms_embed   = (const float*)d_in[0];
    const float* che_nbrs_fea  = (const float*)d_in[1];
    const float* vdw_nbrs_fea  = (const float*)d_in[2];
    const int*   che_nbrs_idx  = (const int*)  d_in[3];
    const int*   vdw_nbrs_idx  = (const int*)  d_in[4];
    const int*   num_atoms     = (const int*)  d_in[5];
    const float* emb_W         = (const float*)d_in[6];
    const float* emb_b         = (const float*)d_in[7];
    const float* che_filter_W  = (const float*)d_in[8];
    const float* che_filter_b  = (const float*)d_in[9];
    const float* che_fc_W      = (const float*)d_in[10];
    const float* che_fc_b      = (const float*)d_in[11];
    const float* vdw_filter_W  = (const float*)d_in[12];
    const float* vdw_filter_b  = (const float*)d_in[13];
    const float* vdw_fc_W      = (const float*)d_in[14];
    const float* vdw_fc_b      = (const float*)d_in[15];
    const float* fc1_W         = (const float*)d_in[16];
    const float* fc1_b         = (const float*)d_in[17];
    const float* out_W         = (const float*)d_in[18];
    const float* out_b         = (const float*)d_in[19];
    float* out = (float*)d_out;

    // workspace layout, ~116 MB
    float* w = (float*)d_ws;
    float* nodesA  = w;                                    // 2.56M f32
    float* nodesB  = nodesA + (size_t)NN * HH;             // 2.56M f32
    float* S       = nodesB + (size_t)NN * HH;             // 10.24M f32
    half2_t* Ypk   = (half2_t*)(S + (size_t)NN * 512);     // 5.12M words
    half2_t* rpk_che = Ypk + (size_t)NN * 256;             // 4M words
    half2_t* rpk_vdw = rpk_che + (size_t)NN * MM * E2;     // 4M words
    float* wbig    = (float*)(rpk_vdw + (size_t)NN * MM * E2); // 393K f32
    half2_t* wcpk  = (half2_t*)(wbig + (size_t)NCONV * 128 * 1024); // 15360 words
    float* bc      = (float*)(wcpk + (size_t)NCONV * 2 * E2 * 2 * 128); // 1536 f32

    prep_wc<<<dim3(E2 + 1, 2, NCONV), 256, 0, stream>>>(
        che_filter_W, che_filter_b, che_fc_W, che_fc_b,
        vdw_filter_W, vdw_filter_b, vdw_fc_W, vdw_fc_b, wcpk, bc);
    prep_wbig<<<(NCONV * 128 * 1024 + 255) / 256, 256, 0, stream>>>(che_fc_W, vdw_fc_W, wbig);
    embed_kernel<<<NN, HH, 0, stream>>>(atoms_embed, emb_W, emb_b, nodesA);
    rbf_kernel<<<(NN * MM + 255) / 256, 256, 0, stream>>>(che_nbrs_fea, rpk_che, NN * MM, CHE_CUT);
    rbf_kernel<<<(NN * MM + 255) / 256, 256, 0, stream>>>(vdw_nbrs_fea, rpk_vdw, NN * MM, VDW_CUT);

    float* cur = nodesA;
    float* nxt = nodesB;
    for (int l = 0; l < NCONV; ++l) {
        gemm_sy<<<dim3(16, (NN + 63) / 64), 256, 0, stream>>>(cur, wbig + (size_t)l * 128 * 1024, S, Ypk, NN);
        edge_kernel<<<NN, HH, 0, stream>>>(
            cur, nxt, S, Ypk, rpk_che, rpk_vdw, che_nbrs_idx, vdw_nbrs_idx,
            wcpk + (size_t)l * 2 * E2 * 2 * 128, bc + (size_t)l * 2 * 256);
        float* tmp = cur; cur = nxt; nxt = tmp;
    }

    pool_kernel<<<BB, HH, 0, stream>>>(cur, num_atoms, fc1_W, fc1_b, out_W, out_b, out);
}

// Round 6
// 814.995 us; speedup vs baseline: 1.6720x; 1.0962x over previous
//
#include <hip/hip_runtime.h>
#include <hip/hip_bf16.h>
#include <math.h>

// Problem constants
#define NN 20000
#define MM 20          // neighbors (same for che and vdw)
#define EE 20          // RBF size
#define E2 10          // EE/2 packed pairs
#define HH 128
#define BB 200
#define NCONV 3
#define CHE_CUT 8.0f
#define VDW_CUT 12.0f
#define PI_F 3.14159265358979323846f

// __builtin_amdgcn_cvt_pkrtz / __builtin_amdgcn_fdot2 use __fp16 vectors
typedef __fp16 half2_t __attribute__((ext_vector_type(2)));
// MFMA f16 builtins use _Float16 vectors
typedef _Float16 f16x8 __attribute__((ext_vector_type(8)));
typedef float f32x4 __attribute__((ext_vector_type(4)));

// ---------------- helpers ---------------------------------------------------
__device__ __forceinline__ float sp_(float x) {
    return (x > 15.f) ? x : __logf(1.f + __expf(x));
}
__device__ __forceinline__ float sig_(float x) {
    return 1.f / (1.f + __expf(-x));
}
__device__ __forceinline__ float fdot2_(half2_t a, half2_t b, float c) {
#if __has_builtin(__builtin_amdgcn_fdot2)
    return __builtin_amdgcn_fdot2(a, b, c, false);
#else
    return (float)a.x * (float)b.x + (float)a.y * (float)b.y + c;
#endif
}

// ---------------- prep: Wc = fW @ gW_edge (packed f16x2 pairs over E) -------
// wcpk layout: [l][half][e2][gate][128]  (gate 0=filt, 1=core)
// bc   layout: [l][half][256] fp32 (gb + fb @ gW_edge)
__global__ void prep_wc(const float* __restrict__ cfW, const float* __restrict__ cfb,
                        const float* __restrict__ cgW, const float* __restrict__ cgb,
                        const float* __restrict__ vfW, const float* __restrict__ vfb,
                        const float* __restrict__ vgW, const float* __restrict__ vgb,
                        half2_t* __restrict__ wcpk, float* __restrict__ bc) {
    int e2 = blockIdx.x;         // 0..E2 (E2 == bias slot)
    int half = blockIdx.y;       // 0=che 1=vdw
    int l = blockIdx.z;
    int j = threadIdx.x;         // 0..255 (= gate*128 + t)
    const float* fW = half ? vfW : cfW;
    const float* fb = half ? vfb : cfb;
    const float* gW = half ? vgW : cgW;
    const float* gb = half ? vgb : cgb;
    const float* gWe = gW + ((size_t)l * 384 + 128) * 256;  // edge rows 128..255
    if (e2 < E2) {
        const float* r0 = fW + ((size_t)l * EE + 2 * e2) * HH;
        const float* r1 = r0 + HH;
        float a0 = 0.f, a1 = 0.f;
        for (int k = 0; k < HH; ++k) {
            float g = gWe[k * 256 + j];
            a0 = fmaf(r0[k], g, a0);
            a1 = fmaf(r1[k], g, a1);
        }
        half2_t p = __builtin_amdgcn_cvt_pkrtz(a0, a1);
        int gate = j >> 7, t = j & 127;
        wcpk[(((size_t)(l * 2 + half) * E2 + e2) * 2 + gate) * 128 + t] = p;
    } else {
        const float* brow = fb + (size_t)l * HH;
        float acc = gb[(size_t)l * 256 + j];
        for (int k = 0; k < HH; ++k) acc = fmaf(brow[k], gWe[k * 256 + j], acc);
        bc[((size_t)l * 2 + half) * 256 + j] = acc;
    }
}

// ---------------- prep: Bpk — B in MFMA B-fragment order, f16 ---------------
// logical columns c (after permutation):
//   c in [  0,256): che self  (gW_self col c)
//   c in [256,512): vdw self  (gW_self col c-256)
//   c in [512,768): che nbr pairs: t=(c-512)>>1, gate=(c-512)&1 -> gW_nbr col gate*128+t
//   c in [768,1024): vdw nbr pairs likewise
// fragment layout: bpk[l][nt][s][lane][j] = B[k = s*32 + (lane>>4)*8 + j][c = nt*16 + (lane&15)]
__global__ void prep_bpk(const float* __restrict__ cgW, const float* __restrict__ vgW,
                         _Float16* __restrict__ bpk) {
    int i = blockIdx.x * 256 + threadIdx.x;
    if (i >= NCONV * 128 * 1024) return;
    int l = i >> 17;
    int rem = i & 131071;
    int k = rem >> 10;         // 0..127
    int c = rem & 1023;
    float val;
    if (c < 512) {
        int half = c >> 8;
        int gcol = c & 255;
        const float* src = half ? vgW : cgW;
        val = src[((size_t)l * 384 + k) * 256 + gcol];
    } else {
        int cc = c - 512;
        int half = cc >> 8;
        int p = cc & 255;
        int gcol = (p & 1) * 128 + (p >> 1);
        const float* src = half ? vgW : cgW;
        val = src[((size_t)l * 384 + 256 + k) * 256 + gcol];
    }
    int nt = c >> 4, n_in = c & 15;
    int s = k >> 5, kq = (k >> 3) & 3, j = k & 7;
    int lane = kq * 16 + n_in;
    bpk[(size_t)l * 131072 + (((size_t)nt * 4 + s) * 64 + lane) * 8 + j] = (_Float16)val;
}

// ---------------- embed -----------------------------------------------------
__global__ void embed_kernel(const float* __restrict__ atoms, const float* __restrict__ W,
                             const float* __restrict__ bias, float* __restrict__ nodes) {
    int n = blockIdx.x, t = threadIdx.x;
    const float* arow = atoms + (size_t)n * 13;
    float acc = bias[t];
    #pragma unroll
    for (int k = 0; k < 13; ++k) acc = fmaf(arow[k], W[k * HH + t], acc);
    nodes[(size_t)n * HH + t] = acc;
}

// ---------------- rbf: packed f16x2 pairs -----------------------------------
__global__ void rbf_kernel(const float* __restrict__ fea, half2_t* __restrict__ rpk,
                           int total, float cutoff) {
    int i = blockIdx.x * blockDim.x + threadIdx.x;
    if (i >= total) return;
    float d = fea[i];
    float x = d * (PI_F / cutoff);
    float s1 = sinf(x), c1 = cosf(x);
    float env = 0.5f * (c1 + 1.f);
    float scale = (d < cutoff) ? (env / d) : 0.f;
    float out[EE];
    float skm1 = 0.f, sk = s1;
    #pragma unroll
    for (int e = 0; e < EE; ++e) {
        out[e] = sk * scale;
        float nx = 2.f * c1 * sk - skm1;
        skm1 = sk; sk = nx;
    }
    half2_t* dst = rpk + (size_t)i * E2;
    #pragma unroll
    for (int e = 0; e < E2; ++e)
        dst[e] = __builtin_amdgcn_cvt_pkrtz(out[2 * e], out[2 * e + 1]);
}

// ---------------- SY GEMM via MFMA: [N,128]@[128,1024] -> S f32 + Ypk f16x2 -
// One wave per 16 rows; B pre-packed in fragment order (L2-resident, 256 KB).
__global__ __launch_bounds__(64)
void gemm_mfma(const float* __restrict__ A, const _Float16* __restrict__ Bpk,
               float* __restrict__ S, half2_t* __restrict__ Ypk) {
    int lane = threadIdx.x;          // 0..63
    int m0 = blockIdx.x * 16;
    int row_a = m0 + (lane & 15);
    int k0 = (lane >> 4) * 8;
    const float* arow = A + (size_t)row_a * 128;

    f16x8 af[4];
    #pragma unroll
    for (int s = 0; s < 4; ++s) {
        float4 lo = *(const float4*)(arow + s * 32 + k0);
        float4 hi = *(const float4*)(arow + s * 32 + k0 + 4);
        f16x8 v;
        v[0] = (_Float16)lo.x; v[1] = (_Float16)lo.y;
        v[2] = (_Float16)lo.z; v[3] = (_Float16)lo.w;
        v[4] = (_Float16)hi.x; v[5] = (_Float16)hi.y;
        v[6] = (_Float16)hi.z; v[7] = (_Float16)hi.w;
        af[s] = v;
    }

    int crow = m0 + ((lane >> 4) << 2);   // + i
    int ccol = lane & 15;
    const f16x8* bpf = (const f16x8*)Bpk;

    for (int nt = 0; nt < 64; ++nt) {
        f32x4 acc = {0.f, 0.f, 0.f, 0.f};
        const f16x8* bp = bpf + ((size_t)nt * 4) * 64 + lane;
        f16x8 b0 = bp[0 * 64], b1 = bp[1 * 64], b2 = bp[2 * 64], b3 = bp[3 * 64];
        acc = __builtin_amdgcn_mfma_f32_16x16x32_f16(af[0], b0, acc, 0, 0, 0);
        acc = __builtin_amdgcn_mfma_f32_16x16x32_f16(af[1], b1, acc, 0, 0, 0);
        acc = __builtin_amdgcn_mfma_f32_16x16x32_f16(af[2], b2, acc, 0, 0, 0);
        acc = __builtin_amdgcn_mfma_f32_16x16x32_f16(af[3], b3, acc, 0, 0, 0);
        if (nt < 32) {
            int c = nt * 16 + ccol;
            #pragma unroll
            for (int i = 0; i < 4; ++i)
                S[(size_t)(crow + i) * 512 + c] = acc[i];
        } else {
            int u = (nt - 32) * 8 + (ccol >> 1);
            #pragma unroll
            for (int i = 0; i < 4; ++i) {
                float v = acc[i];
                float p = __shfl_xor(v, 1, 64);
                if (!(lane & 1)) {
                    half2_t pk = __builtin_amdgcn_cvt_pkrtz(v, p);
                    Ypk[(size_t)(crow + i) * 256 + u] = pk;
                }
            }
        }
    }
}

// ---------------- fused edge + gate + node update ---------------------------
// S  [N][512]: che_filt | che_core | vdw_filt | vdw_core   (fp32, per-node)
// Ypk[N][256]: word t = che (filt,core) f16x2; word 128+t = vdw pair
__global__ __launch_bounds__(128)
void edge_kernel(const float* __restrict__ nodes_in, float* __restrict__ nodes_out,
                 const float* __restrict__ S, const half2_t* __restrict__ Ypk,
                 const half2_t* __restrict__ rpk_che, const half2_t* __restrict__ rpk_vdw,
                 const int* __restrict__ idx_che, const int* __restrict__ idx_vdw,
                 const half2_t* __restrict__ Wcpk,  // [2][E2][2][128] this layer
                 const float* __restrict__ bC) {    // [2][256]
    int t = threadIdx.x;
    int n = blockIdx.x;

    const int* ic = idx_che + (size_t)n * MM;
    const int* iv = idx_vdw + (size_t)n * MM;
    int jc[MM], jv[MM];
    #pragma unroll
    for (int m = 0; m < MM; ++m) jc[m] = ic[m];
    #pragma unroll
    for (int m = 0; m < MM; ++m) jv[m] = iv[m];

    half2_t yw[2 * MM];
    #pragma unroll
    for (int m = 0; m < MM; ++m) yw[m] = Ypk[(size_t)jc[m] * 256 + t];
    #pragma unroll
    for (int m = 0; m < MM; ++m) yw[MM + m] = Ypk[(size_t)jv[m] * 256 + 128 + t];

    const float* srow = S + (size_t)n * 512;
    float sCf = srow[t],       sCc = srow[128 + t];
    float sVf = srow[256 + t], sVc = srow[384 + t];
    float old = nodes_in[(size_t)n * HH + t];

    half2_t wcf[E2], wcc[E2], wvf[E2], wvc[E2];
    #pragma unroll
    for (int e = 0; e < E2; ++e) {
        wcf[e] = Wcpk[((size_t)e * 2 + 0) * 128 + t];
        wcc[e] = Wcpk[((size_t)e * 2 + 1) * 128 + t];
        wvf[e] = Wcpk[((size_t)(E2 + e) * 2 + 0) * 128 + t];
        wvc[e] = Wcpk[((size_t)(E2 + e) * 2 + 1) * 128 + t];
    }
    sCf += bC[t];       sCc += bC[128 + t];
    sVf += bC[256 + t]; sVc += bC[384 + t];

    const half2_t* rc = rpk_che + (size_t)n * (MM * E2);
    const half2_t* rv = rpk_vdw + (size_t)n * (MM * E2);
    float acc = 0.f;

    #pragma unroll
    for (int m = 0; m < MM; ++m) {
        half2_t w = yw[m];
        float gf = sCf + (float)w.x;
        float gc = sCc + (float)w.y;
        const half2_t* r = rc + m * E2;
        #pragma unroll
        for (int e = 0; e < E2; ++e) {
            gf = fdot2_(r[e], wcf[e], gf);
            gc = fdot2_(r[e], wcc[e], gc);
        }
        acc += sig_(gf) * sp_(gc);
    }
    #pragma unroll
    for (int m = 0; m < MM; ++m) {
        half2_t w = yw[MM + m];
        float gf = sVf + (float)w.x;
        float gc = sVc + (float)w.y;
        const half2_t* r = rv + m * E2;
        #pragma unroll
        for (int e = 0; e < E2; ++e) {
            gf = fdot2_(r[e], wvf[e], gf);
            gc = fdot2_(r[e], wvc[e], gc);
        }
        acc += sig_(gf) * sp_(gc);
    }
    nodes_out[(size_t)n * HH + t] = sp_(old + acc);
}

// ---------------- pooling + head MLP ---------------------------------------
__global__ void pool_kernel(const float* __restrict__ nodes, const int* __restrict__ num_atoms,
                            const float* __restrict__ fc1_W, const float* __restrict__ fc1_b,
                            const float* __restrict__ out_W, const float* __restrict__ out_b,
                            float* __restrict__ out) {
    __shared__ float sh[HH];
    __shared__ float red[HH];
    int b = blockIdx.x, t = threadIdx.x;
    int start = 0;
    for (int i = 0; i < b; ++i) start += num_atoms[i];
    int cnt = num_atoms[b];
    float sum = 0.f;
    for (int a = 0; a < cnt; ++a) sum += nodes[(size_t)(start + a) * HH + t];
    float mean = sum / (float)cnt;
    sh[t] = sp_(mean);
    __syncthreads();
    float o = fc1_b[t];
    #pragma unroll 4
    for (int k = 0; k < HH; ++k) o = fmaf(sh[k], fc1_W[k * HH + t], o);
    red[t] = sp_(o) * out_W[t];
    __syncthreads();
    if (t == 0) {
        float tot = 0.f;
        for (int k = 0; k < HH; ++k) tot += red[k];
        out[b] = tot + out_b[0];
    }
}

// ---------------- launch ----------------------------------------------------
extern "C" void kernel_launch(void* const* d_in, const int* in_sizes, int n_in,
                              void* d_out, int out_size, void* d_ws, size_t ws_size,
                              hipStream_t stream) {
    const float* atoms_embed   = (const float*)d_in[0];
    const float* che_nbrs_fea  = (const float*)d_in[1];
    const float* vdw_nbrs_fea  = (const float*)d_in[2];
    const int*   che_nbrs_idx  = (const int*)  d_in[3];
    const int*   vdw_nbrs_idx  = (const int*)  d_in[4];
    const int*   num_atoms     = (const int*)  d_in[5];
    const float* emb_W         = (const float*)d_in[6];
    const float* emb_b         = (const float*)d_in[7];
    const float* che_filter_W  = (const float*)d_in[8];
    const float* che_filter_b  = (const float*)d_in[9];
    const float* che_fc_W      = (const float*)d_in[10];
    const float* che_fc_b      = (const float*)d_in[11];
    const float* vdw_filter_W  = (const float*)d_in[12];
    const float* vdw_filter_b  = (const float*)d_in[13];
    const float* vdw_fc_W      = (const float*)d_in[14];
    const float* vdw_fc_b      = (const float*)d_in[15];
    const float* fc1_W         = (const float*)d_in[16];
    const float* fc1_b         = (const float*)d_in[17];
    const float* out_W         = (const float*)d_in[18];
    const float* out_b         = (const float*)d_in[19];
    float* out = (float*)d_out;

    // workspace layout
    float* w = (float*)d_ws;
    float* nodesA  = w;                                    // 2.56M f32
    float* nodesB  = nodesA + (size_t)NN * HH;             // 2.56M f32
    float* S       = nodesB + (size_t)NN * HH;             // 10.24M f32
    half2_t* Ypk   = (half2_t*)(S + (size_t)NN * 512);     // 5.12M words
    half2_t* rpk_che = Ypk + (size_t)NN * 256;             // 4M words
    half2_t* rpk_vdw = rpk_che + (size_t)NN * MM * E2;     // 4M words
    _Float16* bpk  = (_Float16*)(rpk_vdw + (size_t)NN * MM * E2); // 393216 f16
    half2_t* wcpk  = (half2_t*)(bpk + (size_t)NCONV * 131072);    // 15360 words
    float* bc      = (float*)(wcpk + (size_t)NCONV * 2 * E2 * 2 * 128); // 1536 f32

    prep_wc<<<dim3(E2 + 1, 2, NCONV), 256, 0, stream>>>(
        che_filter_W, che_filter_b, che_fc_W, che_fc_b,
        vdw_filter_W, vdw_filter_b, vdw_fc_W, vdw_fc_b, wcpk, bc);
    prep_bpk<<<(NCONV * 128 * 1024 + 255) / 256, 256, 0, stream>>>(che_fc_W, vdw_fc_W, bpk);
    embed_kernel<<<NN, HH, 0, stream>>>(atoms_embed, emb_W, emb_b, nodesA);
    rbf_kernel<<<(NN * MM + 255) / 256, 256, 0, stream>>>(che_nbrs_fea, rpk_che, NN * MM, CHE_CUT);
    rbf_kernel<<<(NN * MM + 255) / 256, 256, 0, stream>>>(vdw_nbrs_fea, rpk_vdw, NN * MM, VDW_CUT);

    float* cur = nodesA;
    float* nxt = nodesB;
    for (int l = 0; l < NCONV; ++l) {
        gemm_mfma<<<NN / 16, 64, 0, stream>>>(cur, bpk + (size_t)l * 131072, S, Ypk);
        edge_kernel<<<NN, HH, 0, stream>>>(
            cur, nxt, S, Ypk, rpk_che, rpk_vdw, che_nbrs_idx, vdw_nbrs_idx,
            wcpk + (size_t)l * 2 * E2 * 2 * 128, bc + (size_t)l * 2 * 256);
        float* tmp = cur; cur = nxt; nxt = tmp;
    }

    pool_kernel<<<BB, HH, 0, stream>>>(cur, num_atoms, fc1_W, fc1_b, out_W, out_b, out);
}

// Round 7
// 568.149 us; speedup vs baseline: 2.3984x; 1.4345x over previous
//
#include <hip/hip_runtime.h>
#include <hip/hip_bf16.h>
#include <math.h>

// Problem constants
#define NN 20000
#define MM 20          // neighbors (same for che and vdw)
#define EE 20          // RBF size
#define E2 10          // EE/2 packed pairs
#define HH 128
#define BB 200
#define NCONV 3
#define CHE_CUT 8.0f
#define VDW_CUT 12.0f
#define PI_F 3.14159265358979323846f
#define LOG2E_F 1.44269504088896340736f
#define LN2_F 0.69314718055994530942f

// __builtin_amdgcn_cvt_pkrtz / __builtin_amdgcn_fdot2 use __fp16 vectors
typedef __fp16 half2_t __attribute__((ext_vector_type(2)));
// MFMA f16 builtins use _Float16 vectors
typedef _Float16 f16x8 __attribute__((ext_vector_type(8)));
typedef float f32x4 __attribute__((ext_vector_type(4)));

// ---------------- helpers ---------------------------------------------------
__device__ __forceinline__ float exp2_(float x) {
#if __has_builtin(__builtin_amdgcn_exp2f)
    return __builtin_amdgcn_exp2f(x);
#else
    return exp2f(x);
#endif
}
__device__ __forceinline__ float log2_(float x) {
#if __has_builtin(__builtin_amdgcn_logf)
    return __builtin_amdgcn_logf(x);
#else
    return log2f(x);
#endif
}
__device__ __forceinline__ float rcp_(float x) {
#if __has_builtin(__builtin_amdgcn_rcpf)
    return __builtin_amdgcn_rcpf(x);
#else
    return 1.f / x;
#endif
}
__device__ __forceinline__ float sp_(float x) {      // natural-domain softplus
    return (x > 15.f) ? x : LN2_F * log2_(1.f + exp2_(x * LOG2E_F));
}
__device__ __forceinline__ float fdot2_(half2_t a, half2_t b, float c) {
#if __has_builtin(__builtin_amdgcn_fdot2)
    return __builtin_amdgcn_fdot2(a, b, c, false);
#else
    return (float)a.x * (float)b.x + (float)a.y * (float)b.y + c;
#endif
}

// ---------------- prep: Wc = fW @ gW_edge (packed f16x2, scaled by log2e) ---
// wcpk layout: [l][half][e2][gate][128]  (gate 0=filt, 1=core)
// bc   layout: [l][half][256] fp32 (gb + fb @ gW_edge), scaled by log2e
__global__ void prep_wc(const float* __restrict__ cfW, const float* __restrict__ cfb,
                        const float* __restrict__ cgW, const float* __restrict__ cgb,
                        const float* __restrict__ vfW, const float* __restrict__ vfb,
                        const float* __restrict__ vgW, const float* __restrict__ vgb,
                        half2_t* __restrict__ wcpk, float* __restrict__ bc) {
    int e2 = blockIdx.x;         // 0..E2 (E2 == bias slot)
    int half = blockIdx.y;       // 0=che 1=vdw
    int l = blockIdx.z;
    int j = threadIdx.x;         // 0..255 (= gate*128 + t)
    const float* fW = half ? vfW : cfW;
    const float* fb = half ? vfb : cfb;
    const float* gW = half ? vgW : cgW;
    const float* gb = half ? vgb : cgb;
    const float* gWe = gW + ((size_t)l * 384 + 128) * 256;  // edge rows 128..255
    if (e2 < E2) {
        const float* r0 = fW + ((size_t)l * EE + 2 * e2) * HH;
        const float* r1 = r0 + HH;
        float a0 = 0.f, a1 = 0.f;
        for (int k = 0; k < HH; ++k) {
            float g = gWe[k * 256 + j];
            a0 = fmaf(r0[k], g, a0);
            a1 = fmaf(r1[k], g, a1);
        }
        half2_t p = __builtin_amdgcn_cvt_pkrtz(a0 * LOG2E_F, a1 * LOG2E_F);
        int gate = j >> 7, t = j & 127;
        wcpk[(((size_t)(l * 2 + half) * E2 + e2) * 2 + gate) * 128 + t] = p;
    } else {
        const float* brow = fb + (size_t)l * HH;
        float acc = gb[(size_t)l * 256 + j];
        for (int k = 0; k < HH; ++k) acc = fmaf(brow[k], gWe[k * 256 + j], acc);
        bc[((size_t)l * 2 + half) * 256 + j] = acc * LOG2E_F;
    }
}

// ---------------- prep: Bpk — B in MFMA B-fragment order, f16 ---------------
// logical columns c (after permutation):
//   c in [  0,256): che self  (gW_self col c)
//   c in [256,512): vdw self  (gW_self col c-256)
//   c in [512,768): che nbr pairs: t=(c-512)>>1, gate=(c-512)&1 -> gW_nbr col gate*128+t
//   c in [768,1024): vdw nbr pairs likewise
// fragment layout: bpk[l][nt][s][lane][j] = B[k = s*32 + (lane>>4)*8 + j][c = nt*16 + (lane&15)]
__global__ void prep_bpk(const float* __restrict__ cgW, const float* __restrict__ vgW,
                         _Float16* __restrict__ bpk) {
    int i = blockIdx.x * 256 + threadIdx.x;
    if (i >= NCONV * 128 * 1024) return;
    int l = i >> 17;
    int rem = i & 131071;
    int k = rem >> 10;         // 0..127
    int c = rem & 1023;
    float val;
    if (c < 512) {
        int half = c >> 8;
        int gcol = c & 255;
        const float* src = half ? vgW : cgW;
        val = src[((size_t)l * 384 + k) * 256 + gcol];
    } else {
        int cc = c - 512;
        int half = cc >> 8;
        int p = cc & 255;
        int gcol = (p & 1) * 128 + (p >> 1);
        const float* src = half ? vgW : cgW;
        val = src[((size_t)l * 384 + 256 + k) * 256 + gcol];
    }
    int nt = c >> 4, n_in = c & 15;
    int s = k >> 5, kq = (k >> 3) & 3, j = k & 7;
    int lane = kq * 16 + n_in;
    bpk[(size_t)l * 131072 + (((size_t)nt * 4 + s) * 64 + lane) * 8 + j] = (_Float16)val;
}

// ---------------- embed -----------------------------------------------------
__global__ void embed_kernel(const float* __restrict__ atoms, const float* __restrict__ W,
                             const float* __restrict__ bias, float* __restrict__ nodes) {
    int n = blockIdx.x, t = threadIdx.x;
    const float* arow = atoms + (size_t)n * 13;
    float acc = bias[t];
    #pragma unroll
    for (int k = 0; k < 13; ++k) acc = fmaf(arow[k], W[k * HH + t], acc);
    nodes[(size_t)n * HH + t] = acc;
}

// ---------------- rbf: packed f16x2 pairs (NOT scaled; Wc carries log2e) ----
__global__ void rbf_kernel(const float* __restrict__ fea, half2_t* __restrict__ rpk,
                           int total, float cutoff) {
    int i = blockIdx.x * blockDim.x + threadIdx.x;
    if (i >= total) return;
    float d = fea[i];
    float x = d * (PI_F / cutoff);
    float s1 = sinf(x), c1 = cosf(x);
    float env = 0.5f * (c1 + 1.f);
    float scale = (d < cutoff) ? (env / d) : 0.f;
    float out[EE];
    float skm1 = 0.f, sk = s1;
    #pragma unroll
    for (int e = 0; e < EE; ++e) {
        out[e] = sk * scale;
        float nx = 2.f * c1 * sk - skm1;
        skm1 = sk; sk = nx;
    }
    half2_t* dst = rpk + (size_t)i * E2;
    #pragma unroll
    for (int e = 0; e < E2; ++e)
        dst[e] = __builtin_amdgcn_cvt_pkrtz(out[2 * e], out[2 * e + 1]);
}

// ---------------- SY GEMM via MFMA: [N,128]@[128,1024] -> S f32 + Ypk f16x2 -
// 256 threads = 4 waves; wave w handles nt quarter [16w,16w+16).
// A-frags shared rows (L1 reuse); B prefetched depth-1. Outputs scaled log2e.
__global__ __launch_bounds__(256)
void gemm_mfma(const float* __restrict__ A, const _Float16* __restrict__ Bpk,
               float* __restrict__ S, half2_t* __restrict__ Ypk) {
    int lane = threadIdx.x & 63;
    int wv = threadIdx.x >> 6;       // 0..3
    int m0 = blockIdx.x * 16;
    int row_a = m0 + (lane & 15);
    int k0 = (lane >> 4) * 8;
    const float* arow = A + (size_t)row_a * 128;

    f16x8 af[4];
    #pragma unroll
    for (int s = 0; s < 4; ++s) {
        float4 lo = *(const float4*)(arow + s * 32 + k0);
        float4 hi = *(const float4*)(arow + s * 32 + k0 + 4);
        f16x8 v;
        v[0] = (_Float16)lo.x; v[1] = (_Float16)lo.y;
        v[2] = (_Float16)lo.z; v[3] = (_Float16)lo.w;
        v[4] = (_Float16)hi.x; v[5] = (_Float16)hi.y;
        v[6] = (_Float16)hi.z; v[7] = (_Float16)hi.w;
        af[s] = v;
    }

    int crow = m0 + ((lane >> 4) << 2);   // + i
    int ccol = lane & 15;
    const f16x8* bpf = (const f16x8*)Bpk;
    int nt0 = wv * 16, nt1 = nt0 + 16;

    const f16x8* bp0 = bpf + (size_t)nt0 * 256 + lane;
    f16x8 nb0 = bp0[0], nb1 = bp0[64], nb2 = bp0[128], nb3 = bp0[192];

    for (int nt = nt0; nt < nt1; ++nt) {
        f16x8 b0 = nb0, b1 = nb1, b2 = nb2, b3 = nb3;
        if (nt + 1 < nt1) {
            const f16x8* q = bpf + (size_t)(nt + 1) * 256 + lane;
            nb0 = q[0]; nb1 = q[64]; nb2 = q[128]; nb3 = q[192];
        }
        f32x4 acc = {0.f, 0.f, 0.f, 0.f};
        acc = __builtin_amdgcn_mfma_f32_16x16x32_f16(af[0], b0, acc, 0, 0, 0);
        acc = __builtin_amdgcn_mfma_f32_16x16x32_f16(af[1], b1, acc, 0, 0, 0);
        acc = __builtin_amdgcn_mfma_f32_16x16x32_f16(af[2], b2, acc, 0, 0, 0);
        acc = __builtin_amdgcn_mfma_f32_16x16x32_f16(af[3], b3, acc, 0, 0, 0);
        if (nt < 32) {
            int c = nt * 16 + ccol;
            #pragma unroll
            for (int i = 0; i < 4; ++i)
                S[(size_t)(crow + i) * 512 + c] = acc[i] * LOG2E_F;
        } else {
            int u = (nt - 32) * 8 + (ccol >> 1);
            #pragma unroll
            for (int i = 0; i < 4; ++i) {
                float v = acc[i] * LOG2E_F;
                float p = __shfl_xor(v, 1, 64);
                if (!(lane & 1)) {
                    half2_t pk = __builtin_amdgcn_cvt_pkrtz(v, p);
                    Ypk[(size_t)(crow + i) * 256 + u] = pk;
                }
            }
        }
    }
}

// ---------------- fused edge + gate + node update (log2 gate domain) --------
// S  [N][512]: che_filt | che_core | vdw_filt | vdw_core   (fp32, x log2e)
// Ypk[N][256]: word t = che (filt,core) f16x2; word 128+t = vdw pair (x log2e)
__global__ __launch_bounds__(128)
void edge_kernel(const float* __restrict__ nodes_in, float* __restrict__ nodes_out,
                 const float* __restrict__ S, const half2_t* __restrict__ Ypk,
                 const half2_t* __restrict__ rpk_che, const half2_t* __restrict__ rpk_vdw,
                 const int* __restrict__ idx_che, const int* __restrict__ idx_vdw,
                 const half2_t* __restrict__ Wcpk,  // [2][E2][2][128] this layer
                 const float* __restrict__ bC) {    // [2][256]
    int t = threadIdx.x;
    int n = blockIdx.x;

    const int* ic = idx_che + (size_t)n * MM;
    const int* iv = idx_vdw + (size_t)n * MM;
    int jc[MM], jv[MM];
    #pragma unroll
    for (int m = 0; m < MM; ++m) jc[m] = ic[m];
    #pragma unroll
    for (int m = 0; m < MM; ++m) jv[m] = iv[m];

    half2_t yw[2 * MM];
    #pragma unroll
    for (int m = 0; m < MM; ++m) yw[m] = Ypk[(size_t)jc[m] * 256 + t];
    #pragma unroll
    for (int m = 0; m < MM; ++m) yw[MM + m] = Ypk[(size_t)jv[m] * 256 + 128 + t];

    const float* srow = S + (size_t)n * 512;
    float sCf = srow[t],       sCc = srow[128 + t];
    float sVf = srow[256 + t], sVc = srow[384 + t];
    float old = nodes_in[(size_t)n * HH + t];

    half2_t wcf[E2], wcc[E2], wvf[E2], wvc[E2];
    #pragma unroll
    for (int e = 0; e < E2; ++e) {
        wcf[e] = Wcpk[((size_t)e * 2 + 0) * 128 + t];
        wcc[e] = Wcpk[((size_t)e * 2 + 1) * 128 + t];
        wvf[e] = Wcpk[((size_t)(E2 + e) * 2 + 0) * 128 + t];
        wvc[e] = Wcpk[((size_t)(E2 + e) * 2 + 1) * 128 + t];
    }
    sCf += bC[t];       sCc += bC[128 + t];
    sVf += bC[256 + t]; sVc += bC[384 + t];

    const half2_t* rc = rpk_che + (size_t)n * (MM * E2);
    const half2_t* rv = rpk_vdw + (size_t)n * (MM * E2);
    float acc = 0.f;   // accumulates sig(gf) * log2(1+2^gc); x ln2 at the end

    #pragma unroll
    for (int m = 0; m < MM; ++m) {
        half2_t w = yw[m];
        float gf = sCf + (float)w.x;
        float gc = sCc + (float)w.y;
        const half2_t* r = rc + m * E2;
        #pragma unroll
        for (int e = 0; e < E2; ++e) {
            gf = fdot2_(r[e], wcf[e], gf);
            gc = fdot2_(r[e], wcc[e], gc);
        }
        float u = rcp_(1.f + exp2_(-gf));
        float p = log2_(1.f + exp2_(gc));
        p = (gc > 24.f) ? gc : p;
        acc = fmaf(p, u, acc);
    }
    #pragma unroll
    for (int m = 0; m < MM; ++m) {
        half2_t w = yw[MM + m];
        float gf = sVf + (float)w.x;
        float gc = sVc + (float)w.y;
        const half2_t* r = rv + m * E2;
        #pragma unroll
        for (int e = 0; e < E2; ++e) {
            gf = fdot2_(r[e], wvf[e], gf);
            gc = fdot2_(r[e], wvc[e], gc);
        }
        float u = rcp_(1.f + exp2_(-gf));
        float p = log2_(1.f + exp2_(gc));
        p = (gc > 24.f) ? gc : p;
        acc = fmaf(p, u, acc);
    }
    nodes_out[(size_t)n * HH + t] = sp_(fmaf(acc, LN2_F, old));
}

// ---------------- pooling + head MLP ---------------------------------------
__global__ void pool_kernel(const float* __restrict__ nodes, const int* __restrict__ num_atoms,
                            const float* __restrict__ fc1_W, const float* __restrict__ fc1_b,
                            const float* __restrict__ out_W, const float* __restrict__ out_b,
                            float* __restrict__ out) {
    __shared__ float sh[HH];
    __shared__ float red[HH];
    int b = blockIdx.x, t = threadIdx.x;
    int start = 0;
    for (int i = 0; i < b; ++i) start += num_atoms[i];
    int cnt = num_atoms[b];
    float sum = 0.f;
    for (int a = 0; a < cnt; ++a) sum += nodes[(size_t)(start + a) * HH + t];
    float mean = sum / (float)cnt;
    sh[t] = sp_(mean);
    __syncthreads();
    float o = fc1_b[t];
    #pragma unroll 4
    for (int k = 0; k < HH; ++k) o = fmaf(sh[k], fc1_W[k * HH + t], o);
    red[t] = sp_(o) * out_W[t];
    __syncthreads();
    if (t == 0) {
        float tot = 0.f;
        for (int k = 0; k < HH; ++k) tot += red[k];
        out[b] = tot + out_b[0];
    }
}

// ---------------- launch ----------------------------------------------------
extern "C" void kernel_launch(void* const* d_in, const int* in_sizes, int n_in,
                              void* d_out, int out_size, void* d_ws, size_t ws_size,
                              hipStream_t stream) {
    const float* atoms_embed   = (const float*)d_in[0];
    const float* che_nbrs_fea  = (const float*)d_in[1];
    const float* vdw_nbrs_fea  = (const float*)d_in[2];
    const int*   che_nbrs_idx  = (const int*)  d_in[3];
    const int*   vdw_nbrs_idx  = (const int*)  d_in[4];
    const int*   num_atoms     = (const int*)  d_in[5];
    const float* emb_W         = (const float*)d_in[6];
    const float* emb_b         = (const float*)d_in[7];
    const float* che_filter_W  = (const float*)d_in[8];
    const float* che_filter_b  = (const float*)d_in[9];
    const float* che_fc_W      = (const float*)d_in[10];
    const float* che_fc_b      = (const float*)d_in[11];
    const float* vdw_filter_W  = (const float*)d_in[12];
    const float* vdw_filter_b  = (const float*)d_in[13];
    const float* vdw_fc_W      = (const float*)d_in[14];
    const float* vdw_fc_b      = (const float*)d_in[15];
    const float* fc1_W         = (const float*)d_in[16];
    const float* fc1_b         = (const float*)d_in[17];
    const float* out_W         = (const float*)d_in[18];
    const float* out_b         = (const float*)d_in[19];
    float* out = (float*)d_out;

    // workspace layout
    float* w = (float*)d_ws;
    float* nodesA  = w;                                    // 2.56M f32
    float* nodesB  = nodesA + (size_t)NN * HH;             // 2.56M f32
    float* S       = nodesB + (size_t)NN * HH;             // 10.24M f32
    half2_t* Ypk   = (half2_t*)(S + (size_t)NN * 512);     // 5.12M words
    half2_t* rpk_che = Ypk + (size_t)NN * 256;             // 4M words
    half2_t* rpk_vdw = rpk_che + (size_t)NN * MM * E2;     // 4M words
    _Float16* bpk  = (_Float16*)(rpk_vdw + (size_t)NN * MM * E2); // 393216 f16
    half2_t* wcpk  = (half2_t*)(bpk + (size_t)NCONV * 131072);    // 15360 words
    float* bc      = (float*)(wcpk + (size_t)NCONV * 2 * E2 * 2 * 128); // 1536 f32

    prep_wc<<<dim3(E2 + 1, 2, NCONV), 256, 0, stream>>>(
        che_filter_W, che_filter_b, che_fc_W, che_fc_b,
        vdw_filter_W, vdw_filter_b, vdw_fc_W, vdw_fc_b, wcpk, bc);
    prep_bpk<<<(NCONV * 128 * 1024 + 255) / 256, 256, 0, stream>>>(che_fc_W, vdw_fc_W, bpk);
    embed_kernel<<<NN, HH, 0, stream>>>(atoms_embed, emb_W, emb_b, nodesA);
    rbf_kernel<<<(NN * MM + 255) / 256, 256, 0, stream>>>(che_nbrs_fea, rpk_che, NN * MM, CHE_CUT);
    rbf_kernel<<<(NN * MM + 255) / 256, 256, 0, stream>>>(vdw_nbrs_fea, rpk_vdw, NN * MM, VDW_CUT);

    float* cur = nodesA;
    float* nxt = nodesB;
    for (int l = 0; l < NCONV; ++l) {
        gemm_mfma<<<NN / 16, 256, 0, stream>>>(cur, bpk + (size_t)l * 131072, S, Ypk);
        edge_kernel<<<NN, HH, 0, stream>>>(
            cur, nxt, S, Ypk, rpk_che, rpk_vdw, che_nbrs_idx, vdw_nbrs_idx,
            wcpk + (size_t)l * 2 * E2 * 2 * 128, bc + (size_t)l * 2 * 256);
        float* tmp = cur; cur = nxt; nxt = tmp;
    }

    pool_kernel<<<BB, HH, 0, stream>>>(cur, num_atoms, fc1_W, fc1_b, out_W, out_b, out);
}

// Round 8
// 545.235 us; speedup vs baseline: 2.4992x; 1.0420x over previous
//
#include <hip/hip_runtime.h>
#include <hip/hip_bf16.h>
#include <math.h>

// Problem constants
#define NN 20000
#define MM 20          // neighbors (same for che and vdw)
#define EE 20          // RBF size
#define E2 10          // EE/2 packed pairs
#define HH 128
#define BB 200
#define NCONV 3
#define CHE_CUT 8.0f
#define VDW_CUT 12.0f
#define PI_F 3.14159265358979323846f
#define LOG2E_F 1.44269504088896340736f
#define LN2_F 0.69314718055994530942f

// __builtin_amdgcn_cvt_pkrtz / __builtin_amdgcn_fdot2 use __fp16 vectors
typedef __fp16 half2_t __attribute__((ext_vector_type(2)));
// MFMA f16 builtins use _Float16 vectors
typedef _Float16 f16x8 __attribute__((ext_vector_type(8)));
typedef float f32x4 __attribute__((ext_vector_type(4)));

// ---------------- helpers ---------------------------------------------------
__device__ __forceinline__ float exp2_(float x) {
#if __has_builtin(__builtin_amdgcn_exp2f)
    return __builtin_amdgcn_exp2f(x);
#else
    return exp2f(x);
#endif
}
__device__ __forceinline__ float log2_(float x) {
#if __has_builtin(__builtin_amdgcn_logf)
    return __builtin_amdgcn_logf(x);
#else
    return log2f(x);
#endif
}
__device__ __forceinline__ float rcp_(float x) {
#if __has_builtin(__builtin_amdgcn_rcpf)
    return __builtin_amdgcn_rcpf(x);
#else
    return 1.f / x;
#endif
}
__device__ __forceinline__ float sp_(float x) {      // natural-domain softplus
    return (x > 15.f) ? x : LN2_F * log2_(1.f + exp2_(x * LOG2E_F));
}
__device__ __forceinline__ float fdot2_(half2_t a, half2_t b, float c) {
#if __has_builtin(__builtin_amdgcn_fdot2)
    return __builtin_amdgcn_fdot2(a, b, c, false);
#else
    return (float)a.x * (float)b.x + (float)a.y * (float)b.y + c;
#endif
}

// ---------------- prep: Wc = fW @ gW_edge (packed f16x2, scaled by log2e) ---
// wcpk layout: [l][half][e2][gate][128]  (gate 0=filt, 1=core)
// bc   layout: [l][half][256] fp32 (gb + fb @ gW_edge), scaled by log2e
__global__ void prep_wc(const float* __restrict__ cfW, const float* __restrict__ cfb,
                        const float* __restrict__ cgW, const float* __restrict__ cgb,
                        const float* __restrict__ vfW, const float* __restrict__ vfb,
                        const float* __restrict__ vgW, const float* __restrict__ vgb,
                        half2_t* __restrict__ wcpk, float* __restrict__ bc) {
    int e2 = blockIdx.x;         // 0..E2 (E2 == bias slot)
    int half = blockIdx.y;       // 0=che 1=vdw
    int l = blockIdx.z;
    int j = threadIdx.x;         // 0..255 (= gate*128 + t)
    const float* fW = half ? vfW : cfW;
    const float* fb = half ? vfb : cfb;
    const float* gW = half ? vgW : cgW;
    const float* gb = half ? vgb : cgb;
    const float* gWe = gW + ((size_t)l * 384 + 128) * 256;  // edge rows 128..255
    if (e2 < E2) {
        const float* r0 = fW + ((size_t)l * EE + 2 * e2) * HH;
        const float* r1 = r0 + HH;
        float a0 = 0.f, a1 = 0.f;
        for (int k = 0; k < HH; ++k) {
            float g = gWe[k * 256 + j];
            a0 = fmaf(r0[k], g, a0);
            a1 = fmaf(r1[k], g, a1);
        }
        half2_t p = __builtin_amdgcn_cvt_pkrtz(a0 * LOG2E_F, a1 * LOG2E_F);
        int gate = j >> 7, t = j & 127;
        wcpk[(((size_t)(l * 2 + half) * E2 + e2) * 2 + gate) * 128 + t] = p;
    } else {
        const float* brow = fb + (size_t)l * HH;
        float acc = gb[(size_t)l * 256 + j];
        for (int k = 0; k < HH; ++k) acc = fmaf(brow[k], gWe[k * 256 + j], acc);
        bc[((size_t)l * 2 + half) * 256 + j] = acc * LOG2E_F;
    }
}

// ---------------- prep: Bpk — B in MFMA B-fragment order, f16, x log2e ------
// column order (identity regions):
//   c in [  0,256): che self  (gW rows 0..127,  col c&255)
//   c in [256,512): vdw self
//   c in [512,768): che nbr   (gW rows 256..383, col c&255)
//   c in [768,1024): vdw nbr
// fragment layout: bpk[l][nt][s][lane][j] = B[k = s*32 + (lane>>4)*8 + j][c = nt*16 + (lane&15)]
__global__ void prep_bpk(const float* __restrict__ cgW, const float* __restrict__ vgW,
                         _Float16* __restrict__ bpk) {
    int i = blockIdx.x * 256 + threadIdx.x;
    if (i >= NCONV * 128 * 1024) return;
    int l = i >> 17;
    int rem = i & 131071;
    int k = rem >> 10;         // 0..127
    int c = rem & 1023;
    int half = (c >> 8) & 1;   // regions: che,vdw,che,vdw
    const float* src = half ? vgW : cgW;
    int grow = l * 384 + ((c < 512) ? k : 256 + k);
    float val = src[(size_t)grow * 256 + (c & 255)] * LOG2E_F;
    int nt = c >> 4, nc = c & 15;
    int s = k >> 5, kq = (k >> 3) & 3, j = k & 7;
    bpk[(size_t)l * 131072 + (((size_t)nt * 4 + s) * 64 + kq * 16 + nc) * 8 + j] = (_Float16)val;
}

// ---------------- embed: f32 nodes + f16 copy for the GEMM ------------------
__global__ void embed_kernel(const float* __restrict__ atoms, const float* __restrict__ W,
                             const float* __restrict__ bias, float* __restrict__ nodes,
                             _Float16* __restrict__ nodes_h) {
    int n = blockIdx.x, t = threadIdx.x;
    const float* arow = atoms + (size_t)n * 13;
    float acc = bias[t];
    #pragma unroll
    for (int k = 0; k < 13; ++k) acc = fmaf(arow[k], W[k * HH + t], acc);
    nodes[(size_t)n * HH + t] = acc;
    nodes_h[(size_t)n * HH + t] = (_Float16)acc;
}

// ---------------- rbf (merged che+vdw): packed f16x2 pairs ------------------
__global__ void rbf_kernel(const float* __restrict__ che_fea, const float* __restrict__ vdw_fea,
                           half2_t* __restrict__ rpk) {
    int i = blockIdx.x * blockDim.x + threadIdx.x;
    if (i >= 2 * NN * MM) return;
    bool isv = i >= NN * MM;
    float d = isv ? vdw_fea[i - NN * MM] : che_fea[i];
    float cutoff = isv ? VDW_CUT : CHE_CUT;
    float x = d * (PI_F / cutoff);
    float s1 = sinf(x), c1 = cosf(x);
    float env = 0.5f * (c1 + 1.f);
    float scale = (d < cutoff) ? (env / d) : 0.f;
    float out[EE];
    float skm1 = 0.f, sk = s1;
    #pragma unroll
    for (int e = 0; e < EE; ++e) {
        out[e] = sk * scale;
        float nx = 2.f * c1 * sk - skm1;
        skm1 = sk; sk = nx;
    }
    half2_t* dst = rpk + (size_t)i * E2;
    #pragma unroll
    for (int e = 0; e < E2; ++e)
        dst[e] = __builtin_amdgcn_cvt_pkrtz(out[2 * e], out[2 * e + 1]);
}

// ---------------- SY GEMM via MFMA: [N,128]@[128,1024] -> Spk + Ypk f16x2 ---
// 625 blocks x 4 waves; M=32 rows/block. Wave wv handles gate pair tiles
// (wv*16+p, wv*16+8+p), p=0..7 -> (filt,core) of one channel in SAME lane.
// wv 0: che-S, 1: vdw-S, 2: che-Y, 3: vdw-Y. All values pre-scaled by log2e.
__global__ __launch_bounds__(256)
void gemm_mfma(const _Float16* __restrict__ Ah, const _Float16* __restrict__ Bpk,
               half2_t* __restrict__ Spk, half2_t* __restrict__ Ypk) {
    int lane = threadIdx.x & 63;
    int wv = threadIdx.x >> 6;       // 0..3
    int m0 = blockIdx.x * 32;
    int la = lane & 15;
    int quad = lane >> 4;
    int k0 = quad * 8;

    f16x8 af[2][4];
    #pragma unroll
    for (int rt = 0; rt < 2; ++rt) {
        const _Float16* arow = Ah + (size_t)(m0 + rt * 16 + la) * 128 + k0;
        #pragma unroll
        for (int s = 0; s < 4; ++s)
            af[rt][s] = *(const f16x8*)(arow + s * 32);
    }

    const f16x8* bp = (const f16x8*)Bpk;
    int ntf0 = wv * 16;
    half2_t* dst = (wv & 2) ? Ypk : Spk;
    int wbase = (wv & 1) * 128 + la;

    f16x8 fb[4], cb[4], nfb[4], ncb[4];
    #pragma unroll
    for (int s = 0; s < 4; ++s) {
        fb[s] = bp[((size_t)ntf0 * 4 + s) * 64 + lane];
        cb[s] = bp[((size_t)(ntf0 + 8) * 4 + s) * 64 + lane];
    }
    for (int p = 0; p < 8; ++p) {
        if (p < 7) {
            #pragma unroll
            for (int s = 0; s < 4; ++s) {
                nfb[s] = bp[((size_t)(ntf0 + p + 1) * 4 + s) * 64 + lane];
                ncb[s] = bp[((size_t)(ntf0 + 9 + p) * 4 + s) * 64 + lane];
            }
        }
        #pragma unroll
        for (int rt = 0; rt < 2; ++rt) {
            f32x4 accf = {0.f, 0.f, 0.f, 0.f};
            f32x4 accc = {0.f, 0.f, 0.f, 0.f};
            #pragma unroll
            for (int s = 0; s < 4; ++s) {
                accf = __builtin_amdgcn_mfma_f32_16x16x32_f16(af[rt][s], fb[s], accf, 0, 0, 0);
                accc = __builtin_amdgcn_mfma_f32_16x16x32_f16(af[rt][s], cb[s], accc, 0, 0, 0);
            }
            int row = m0 + rt * 16 + quad * 4;
            int word = wbase + p * 16;
            #pragma unroll
            for (int i = 0; i < 4; ++i) {
                half2_t pk = __builtin_amdgcn_cvt_pkrtz(accf[i], accc[i]);
                dst[(size_t)(row + i) * 256 + word] = pk;
            }
        }
        #pragma unroll
        for (int s = 0; s < 4; ++s) { fb[s] = nfb[s]; cb[s] = ncb[s]; }
    }
}

// ---------------- fused edge + gate + node update (log2 gate domain) --------
// Spk[N][256]: word t = che (filt,core) f16x2 self; word 128+t = vdw pair
// Ypk[N][256]: word t = che (filt,core) f16x2 nbr;  word 128+t = vdw pair
__global__ __launch_bounds__(128)
void edge_kernel(const float* __restrict__ nodes_in, float* __restrict__ nodes_out,
                 _Float16* __restrict__ nodes_h,
                 const half2_t* __restrict__ Spk, const half2_t* __restrict__ Ypk,
                 const half2_t* __restrict__ rpk,
                 const int* __restrict__ idx_che, const int* __restrict__ idx_vdw,
                 const half2_t* __restrict__ Wcpk,  // [2][E2][2][128] this layer
                 const float* __restrict__ bC) {    // [2][256]
    int t = threadIdx.x;
    int n = blockIdx.x;

    const int* ic = idx_che + (size_t)n * MM;
    const int* iv = idx_vdw + (size_t)n * MM;
    int jc[MM], jv[MM];
    #pragma unroll
    for (int m = 0; m < MM; ++m) jc[m] = ic[m];
    #pragma unroll
    for (int m = 0; m < MM; ++m) jv[m] = iv[m];

    half2_t yw[2 * MM];
    #pragma unroll
    for (int m = 0; m < MM; ++m) yw[m] = Ypk[(size_t)jc[m] * 256 + t];
    #pragma unroll
    for (int m = 0; m < MM; ++m) yw[MM + m] = Ypk[(size_t)jv[m] * 256 + 128 + t];

    half2_t spc = Spk[(size_t)n * 256 + t];
    half2_t spv = Spk[(size_t)n * 256 + 128 + t];
    float old = nodes_in[(size_t)n * HH + t];

    half2_t wcf[E2], wcc[E2], wvf[E2], wvc[E2];
    #pragma unroll
    for (int e = 0; e < E2; ++e) {
        wcf[e] = Wcpk[((size_t)e * 2 + 0) * 128 + t];
        wcc[e] = Wcpk[((size_t)e * 2 + 1) * 128 + t];
        wvf[e] = Wcpk[((size_t)(E2 + e) * 2 + 0) * 128 + t];
        wvc[e] = Wcpk[((size_t)(E2 + e) * 2 + 1) * 128 + t];
    }
    float sCf = bC[t] + (float)spc.x;
    float sCc = bC[128 + t] + (float)spc.y;
    float sVf = bC[256 + t] + (float)spv.x;
    float sVc = bC[384 + t] + (float)spv.y;

    const half2_t ONE0 = {(__fp16)1.f, (__fp16)0.f};
    const half2_t ZERO1 = {(__fp16)0.f, (__fp16)1.f};
    const half2_t* rc = rpk + (size_t)n * (MM * E2);
    const half2_t* rv = rpk + ((size_t)NN * MM + (size_t)n * MM) * E2;
    float acc = 0.f;   // accumulates sig(gf) * log2(1+2^gc); x ln2 at the end

    #pragma unroll
    for (int m = 0; m < MM; ++m) {
        half2_t w = yw[m];
        float gf = fdot2_(w, ONE0, sCf);
        float gc = fdot2_(w, ZERO1, sCc);
        const half2_t* r = rc + m * E2;
        #pragma unroll
        for (int e = 0; e < E2; ++e) {
            gf = fdot2_(r[e], wcf[e], gf);
            gc = fdot2_(r[e], wcc[e], gc);
        }
        float u = rcp_(1.f + exp2_(-gf));
        float p = log2_(1.f + exp2_(gc));
        p = (gc > 24.f) ? gc : p;
        acc = fmaf(p, u, acc);
    }
    #pragma unroll
    for (int m = 0; m < MM; ++m) {
        half2_t w = yw[MM + m];
        float gf = fdot2_(w, ONE0, sVf);
        float gc = fdot2_(w, ZERO1, sVc);
        const half2_t* r = rv + m * E2;
        #pragma unroll
        for (int e = 0; e < E2; ++e) {
            gf = fdot2_(r[e], wvf[e], gf);
            gc = fdot2_(r[e], wvc[e], gc);
        }
        float u = rcp_(1.f + exp2_(-gf));
        float p = log2_(1.f + exp2_(gc));
        p = (gc > 24.f) ? gc : p;
        acc = fmaf(p, u, acc);
    }
    float res = sp_(fmaf(acc, LN2_F, old));
    nodes_out[(size_t)n * HH + t] = res;
    nodes_h[(size_t)n * HH + t] = (_Float16)res;
}

// ---------------- pooling + head MLP ---------------------------------------
__global__ void pool_kernel(const float* __restrict__ nodes, const int* __restrict__ num_atoms,
                            const float* __restrict__ fc1_W, const float* __restrict__ fc1_b,
                            const float* __restrict__ out_W, const float* __restrict__ out_b,
                            float* __restrict__ out) {
    __shared__ float sh[HH];
    __shared__ float red[HH];
    int b = blockIdx.x, t = threadIdx.x;
    int start = 0;
    for (int i = 0; i < b; ++i) start += num_atoms[i];
    int cnt = num_atoms[b];
    float sum = 0.f;
    for (int a = 0; a < cnt; ++a) sum += nodes[(size_t)(start + a) * HH + t];
    float mean = sum / (float)cnt;
    sh[t] = sp_(mean);
    __syncthreads();
    float o = fc1_b[t];
    #pragma unroll 4
    for (int k = 0; k < HH; ++k) o = fmaf(sh[k], fc1_W[k * HH + t], o);
    red[t] = sp_(o) * out_W[t];
    __syncthreads();
    if (t == 0) {
        float tot = 0.f;
        for (int k = 0; k < HH; ++k) tot += red[k];
        out[b] = tot + out_b[0];
    }
}

// ---------------- launch ----------------------------------------------------
extern "C" void kernel_launch(void* const* d_in, const int* in_sizes, int n_in,
                              void* d_out, int out_size, void* d_ws, size_t ws_size,
                              hipStream_t stream) {
    const float* atoms_embed   = (const float*)d_in[0];
    const float* che_nbrs_fea  = (const float*)d_in[1];
    const float* vdw_nbrs_fea  = (const float*)d_in[2];
    const int*   che_nbrs_idx  = (const int*)  d_in[3];
    const int*   vdw_nbrs_idx  = (const int*)  d_in[4];
    const int*   num_atoms     = (const int*)  d_in[5];
    const float* emb_W         = (const float*)d_in[6];
    const float* emb_b         = (const float*)d_in[7];
    const float* che_filter_W  = (const float*)d_in[8];
    const float* che_filter_b  = (const float*)d_in[9];
    const float* che_fc_W      = (const float*)d_in[10];
    const float* che_fc_b      = (const float*)d_in[11];
    const float* vdw_filter_W  = (const float*)d_in[12];
    const float* vdw_filter_b  = (const float*)d_in[13];
    const float* vdw_fc_W      = (const float*)d_in[14];
    const float* vdw_fc_b      = (const float*)d_in[15];
    const float* fc1_W         = (const float*)d_in[16];
    const float* fc1_b         = (const float*)d_in[17];
    const float* out_W         = (const float*)d_in[18];
    const float* out_b         = (const float*)d_in[19];
    float* out = (float*)d_out;

    // workspace layout (~100 MB)
    float* w = (float*)d_ws;
    float* nodesA   = w;                                       // NN*HH f32
    float* nodesB   = nodesA + (size_t)NN * HH;                // NN*HH f32
    _Float16* nodes_h = (_Float16*)(nodesB + (size_t)NN * HH); // NN*HH f16
    half2_t* Spk    = (half2_t*)(nodes_h + (size_t)NN * HH);   // NN*256 words
    half2_t* Ypk    = Spk + (size_t)NN * 256;                  // NN*256 words
    half2_t* rpk    = Ypk + (size_t)NN * 256;                  // 2*NN*MM*E2 words
    _Float16* bpk   = (_Float16*)(rpk + (size_t)2 * NN * MM * E2); // NCONV*131072
    half2_t* wcpk   = (half2_t*)(bpk + (size_t)NCONV * 131072);    // 15360 words
    float* bc       = (float*)(wcpk + (size_t)NCONV * 2 * E2 * 2 * 128); // 1536 f32

    prep_wc<<<dim3(E2 + 1, 2, NCONV), 256, 0, stream>>>(
        che_filter_W, che_filter_b, che_fc_W, che_fc_b,
        vdw_filter_W, vdw_filter_b, vdw_fc_W, vdw_fc_b, wcpk, bc);
    prep_bpk<<<(NCONV * 128 * 1024 + 255) / 256, 256, 0, stream>>>(che_fc_W, vdw_fc_W, bpk);
    embed_kernel<<<NN, HH, 0, stream>>>(atoms_embed, emb_W, emb_b, nodesA, nodes_h);
    rbf_kernel<<<(2 * NN * MM + 255) / 256, 256, 0, stream>>>(che_nbrs_fea, vdw_nbrs_fea, rpk);

    float* cur = nodesA;
    float* nxt = nodesB;
    for (int l = 0; l < NCONV; ++l) {
        gemm_mfma<<<NN / 32, 256, 0, stream>>>(nodes_h, bpk + (size_t)l * 131072, Spk, Ypk);
        edge_kernel<<<NN, HH, 0, stream>>>(
            cur, nxt, nodes_h, Spk, Ypk, rpk, che_nbrs_idx, vdw_nbrs_idx,
            wcpk + (size_t)l * 2 * E2 * 2 * 128, bc + (size_t)l * 2 * 256);
        float* tmp = cur; cur = nxt; nxt = tmp;
    }

    pool_kernel<<<BB, HH, 0, stream>>>(cur, num_atoms, fc1_W, fc1_b, out_W, out_b, out);
}

// Round 10
// 541.122 us; speedup vs baseline: 2.5182x; 1.0076x over previous
//
#include <hip/hip_runtime.h>
#include <hip/hip_bf16.h>
#include <math.h>

// Problem constants
#define NN 20000
#define MM 20          // neighbors (same for che and vdw)
#define EE 20          // RBF size
#define HH 128
#define BB 200
#define NCONV 3
#define CHE_CUT 8.0f
#define VDW_CUT 12.0f
#define PI_F 3.14159265358979323846f
#define LOG2E_F 1.44269504088896340736f
#define LN2_F 0.69314718055994530942f

// __builtin_amdgcn_cvt_pkrtz / __builtin_amdgcn_fdot2 use __fp16 vectors
typedef __fp16 half2_t __attribute__((ext_vector_type(2)));
// MFMA f16 builtins use _Float16 vectors
typedef _Float16 f16x8 __attribute__((ext_vector_type(8)));
typedef float f32x4 __attribute__((ext_vector_type(4)));

// ---------------- helpers ---------------------------------------------------
__device__ __forceinline__ float exp2_(float x) {
#if __has_builtin(__builtin_amdgcn_exp2f)
    return __builtin_amdgcn_exp2f(x);
#else
    return exp2f(x);
#endif
}
__device__ __forceinline__ float log2_(float x) {
#if __has_builtin(__builtin_amdgcn_logf)
    return __builtin_amdgcn_logf(x);
#else
    return log2f(x);
#endif
}
__device__ __forceinline__ float rcp_(float x) {
#if __has_builtin(__builtin_amdgcn_rcpf)
    return __builtin_amdgcn_rcpf(x);
#else
    return 1.f / x;
#endif
}
__device__ __forceinline__ float sp_(float x) {      // natural-domain softplus
    return (x > 15.f) ? x : LN2_F * log2_(1.f + exp2_(x * LOG2E_F));
}
__device__ __forceinline__ float fdot2_(half2_t a, half2_t b, float c) {
#if __has_builtin(__builtin_amdgcn_fdot2)
    return __builtin_amdgcn_fdot2(a, b, c, false);
#else
    return (float)a.x * (float)b.x + (float)a.y * (float)b.y + c;
#endif
}

// ---------------- prep: bc = (gb + fb @ gW_edge) * log2e --------------------
// bc layout: [l][half][gate*128+t] fp32
__global__ void prep_bias(const float* __restrict__ cfb, const float* __restrict__ cgW,
                          const float* __restrict__ cgb,
                          const float* __restrict__ vfb, const float* __restrict__ vgW,
                          const float* __restrict__ vgb, float* __restrict__ bc) {
    int half = blockIdx.y;
    int l = blockIdx.z;
    int j = threadIdx.x;         // 0..255
    const float* fb = half ? vfb : cfb;
    const float* gW = half ? vgW : cgW;
    const float* gb = half ? vgb : cgb;
    const float* gWe = gW + ((size_t)l * 384 + 128) * 256;
    const float* brow = fb + (size_t)l * HH;
    float acc = gb[(size_t)l * 256 + j];
    for (int k = 0; k < HH; ++k) acc = fmaf(brow[k], gWe[k * 256 + j], acc);
    bc[((size_t)l * 2 + half) * 256 + j] = acc * LOG2E_F;
}

// ---------------- prep: bwc — Wc=fW@gW_edge in MFMA B-fragment order --------
// columns c = 2t+gate (gate 0=filt, 1=core); k = e (0..19), pad 20..31 ZERO.
// bwc[l][h][nt(16)][lane(64)][8]: value = Wc[k][c], lane = (k>>3)*16 + (c&15), j=k&7
__global__ void prep_bwc(const float* __restrict__ cfW, const float* __restrict__ cgW,
                         const float* __restrict__ vfW, const float* __restrict__ vgW,
                         _Float16* __restrict__ bwc) {
    int nt = blockIdx.x;         // 0..15
    int half = blockIdx.y;
    int l = blockIdx.z;
    int tid = threadIdx.x;       // 0..511: k = tid>>4, nc = tid&15
    int k = tid >> 4, nc = tid & 15;
    int c = nt * 16 + nc;
    int t = c >> 1, gate = c & 1;
    int gcol = gate * 128 + t;
    const float* fW = half ? vfW : cfW;
    const float* gW = half ? vgW : cgW;
    const float* gWe = gW + ((size_t)l * 384 + 128) * 256;
    float val = 0.f;
    if (k < EE) {
        const float* frow = fW + ((size_t)l * EE + k) * HH;
        for (int kk = 0; kk < HH; ++kk) val = fmaf(frow[kk], gWe[kk * 256 + gcol], val);
        val *= LOG2E_F;
    }
    bwc[(((size_t)(l * 2 + half) * 16 + nt) * 64 + (k >> 3) * 16 + nc) * 8 + (k & 7)] = (_Float16)val;
}

// ---------------- prep: Bpk — B in MFMA B-fragment order, f16, x log2e ------
// column order (identity regions): [cheS|vdwS|cheY|vdwY]
__global__ void prep_bpk(const float* __restrict__ cgW, const float* __restrict__ vgW,
                         _Float16* __restrict__ bpk) {
    int i = blockIdx.x * 256 + threadIdx.x;
    if (i >= NCONV * 128 * 1024) return;
    int l = i >> 17;
    int rem = i & 131071;
    int k = rem >> 10;         // 0..127
    int c = rem & 1023;
    int half = (c >> 8) & 1;   // regions: che,vdw,che,vdw
    const float* src = half ? vgW : cgW;
    int grow = l * 384 + ((c < 512) ? k : 256 + k);
    float val = src[(size_t)grow * 256 + (c & 255)] * LOG2E_F;
    int nt = c >> 4, nc = c & 15;
    int s = k >> 5, kq = (k >> 3) & 3, j = k & 7;
    bpk[(size_t)l * 131072 + (((size_t)nt * 4 + s) * 64 + kq * 16 + nc) * 8 + j] = (_Float16)val;
}

// ---------------- embed: f32 nodes + f16 copy for the GEMM ------------------
__global__ void embed_kernel(const float* __restrict__ atoms, const float* __restrict__ W,
                             const float* __restrict__ bias, float* __restrict__ nodes,
                             _Float16* __restrict__ nodes_h) {
    int n = blockIdx.x, t = threadIdx.x;
    const float* arow = atoms + (size_t)n * 13;
    float acc = bias[t];
    #pragma unroll
    for (int k = 0; k < 13; ++k) acc = fmaf(arow[k], W[k * HH + t], acc);
    nodes[(size_t)n * HH + t] = acc;
    nodes_h[(size_t)n * HH + t] = (_Float16)acc;
}

// ---------------- rbf: write straight into per-node A-fragment order --------
// rfrag[h][n][mt(2)][lane(64)][8] f16;  A[m][k]: m=(lane&15)+16*mt, k=(lane>>4)*8+j
// k=20..31 written as explicit zeros. mt=1 lanes la>=4 (rows 20..31) are
// zero-filled by the hipMemsetAsync in kernel_launch (content inert anyway,
// but replay must be a pure function of inputs — tripwire lesson, R9).
__global__ void rbf_kernel(const float* __restrict__ che_fea, const float* __restrict__ vdw_fea,
                           _Float16* __restrict__ rfrag) {
    int i = blockIdx.x * blockDim.x + threadIdx.x;
    if (i >= 2 * NN * MM) return;
    bool isv = i >= NN * MM;
    int rem = isv ? i - NN * MM : i;
    int n = rem / MM, m = rem % MM;
    float d = isv ? vdw_fea[rem] : che_fea[rem];
    float cutoff = isv ? VDW_CUT : CHE_CUT;
    float x = d * (PI_F / cutoff);
    float s1 = sinf(x), c1 = cosf(x);
    float env = 0.5f * (c1 + 1.f);
    float scale = (d < cutoff) ? (env / d) : 0.f;
    float out[EE];
    float skm1 = 0.f, sk = s1;
    #pragma unroll
    for (int e = 0; e < EE; ++e) {
        out[e] = sk * scale;
        float nx = 2.f * c1 * sk - skm1;
        skm1 = sk; sk = nx;
    }
    int mt = m >> 4, la = m & 15;
    _Float16* base = rfrag + (((size_t)(isv ? NN + n : n) * 2 + mt) * 64) * 8 + la * 8;
    f16x8 v0, v1, v2, v3;
    #pragma unroll
    for (int j = 0; j < 8; ++j) {
        v0[j] = (_Float16)out[j];
        v1[j] = (_Float16)out[8 + j];
        v2[j] = (j < 4) ? (_Float16)out[16 + j] : (_Float16)0.f;
        v3[j] = (_Float16)0.f;
    }
    *(f16x8*)(base) = v0;             // quad 0 (k 0..7)
    *(f16x8*)(base + 128) = v1;       // quad 1 (k 8..15)
    *(f16x8*)(base + 256) = v2;       // quad 2 (k 16..23, 20+ zero)
    *(f16x8*)(base + 384) = v3;       // quad 3 (k 24..31, zero)
}

// ---------------- SY GEMM via MFMA: [N,128]@[128,1024] -> Spk + Ypk f16x2 ---
// 625 blocks x 4 waves; M=32 rows/block. Wave wv handles gate pair tiles
// (wv*16+p, wv*16+8+p), p=0..7 -> (filt,core) of one channel in SAME lane.
// wv 0: che-S, 1: vdw-S, 2: che-Y, 3: vdw-Y. All values pre-scaled by log2e.
__global__ __launch_bounds__(256)
void gemm_mfma(const _Float16* __restrict__ Ah, const _Float16* __restrict__ Bpk,
               half2_t* __restrict__ Spk, half2_t* __restrict__ Ypk) {
    int lane = threadIdx.x & 63;
    int wv = threadIdx.x >> 6;       // 0..3
    int m0 = blockIdx.x * 32;
    int la = lane & 15;
    int quad = lane >> 4;
    int k0 = quad * 8;

    f16x8 af[2][4];
    #pragma unroll
    for (int rt = 0; rt < 2; ++rt) {
        const _Float16* arow = Ah + (size_t)(m0 + rt * 16 + la) * 128 + k0;
        #pragma unroll
        for (int s = 0; s < 4; ++s)
            af[rt][s] = *(const f16x8*)(arow + s * 32);
    }

    const f16x8* bp = (const f16x8*)Bpk;
    int ntf0 = wv * 16;
    half2_t* dst = (wv & 2) ? Ypk : Spk;
    int wbase = (wv & 1) * 128 + la;

    f16x8 fb[4], cb[4], nfb[4], ncb[4];
    #pragma unroll
    for (int s = 0; s < 4; ++s) {
        fb[s] = bp[((size_t)ntf0 * 4 + s) * 64 + lane];
        cb[s] = bp[((size_t)(ntf0 + 8) * 4 + s) * 64 + lane];
    }
    for (int p = 0; p < 8; ++p) {
        if (p < 7) {
            #pragma unroll
            for (int s = 0; s < 4; ++s) {
                nfb[s] = bp[((size_t)(ntf0 + p + 1) * 4 + s) * 64 + lane];
                ncb[s] = bp[((size_t)(ntf0 + 9 + p) * 4 + s) * 64 + lane];
            }
        }
        #pragma unroll
        for (int rt = 0; rt < 2; ++rt) {
            f32x4 accf = {0.f, 0.f, 0.f, 0.f};
            f32x4 accc = {0.f, 0.f, 0.f, 0.f};
            #pragma unroll
            for (int s = 0; s < 4; ++s) {
                accf = __builtin_amdgcn_mfma_f32_16x16x32_f16(af[rt][s], fb[s], accf, 0, 0, 0);
                accc = __builtin_amdgcn_mfma_f32_16x16x32_f16(af[rt][s], cb[s], accc, 0, 0, 0);
            }
            int row = m0 + rt * 16 + quad * 4;
            int word = wbase + p * 16;
            #pragma unroll
            for (int i = 0; i < 4; ++i) {
                half2_t pk = __builtin_amdgcn_cvt_pkrtz(accf[i], accc[i]);
                dst[(size_t)(row + i) * 256 + word] = pk;
            }
        }
        #pragma unroll
        for (int s = 0; s < 4; ++s) { fb[s] = nfb[s]; cb[s] = ncb[s]; }
    }
}

// ---------------- fused edge: MFMA contraction + LDS + gate + update --------
// Per block: one node. Phase1 (per half): G[m][c=2t+gate] = rbf @ Wc via MFMA
// -> LDS. Phase2: thread t reads (gf,gc) pairs, adds S/Y/bias, activations.
__global__ __launch_bounds__(128)
void edge_kernel(const float* __restrict__ nodes_in, float* __restrict__ nodes_out,
                 _Float16* __restrict__ nodes_h,
                 const half2_t* __restrict__ Spk, const half2_t* __restrict__ Ypk,
                 const _Float16* __restrict__ rfrag,
                 const int* __restrict__ idx_che, const int* __restrict__ idx_vdw,
                 const _Float16* __restrict__ bwc,  // this layer: [2][16][64][8]
                 const float* __restrict__ bC) {    // [2][256]
    __shared__ float G[32 * 256];                   // 32 KB
    int t = threadIdx.x;
    int lane = t & 63;
    int wv = t >> 6;
    int n = blockIdx.x;

    const int* ic = idx_che + (size_t)n * MM;
    const int* iv = idx_vdw + (size_t)n * MM;
    int jc[MM], jv[MM];
    #pragma unroll
    for (int m = 0; m < MM; ++m) jc[m] = ic[m];
    #pragma unroll
    for (int m = 0; m < MM; ++m) jv[m] = iv[m];

    // batch all 40 gathers up front (overlap the MFMA phase)
    half2_t yw[2 * MM];
    #pragma unroll
    for (int m = 0; m < MM; ++m) yw[m] = Ypk[(size_t)jc[m] * 256 + t];
    #pragma unroll
    for (int m = 0; m < MM; ++m) yw[MM + m] = Ypk[(size_t)jv[m] * 256 + 128 + t];

    half2_t spc = Spk[(size_t)n * 256 + t];
    half2_t spv = Spk[(size_t)n * 256 + 128 + t];
    float old = nodes_in[(size_t)n * HH + t];
    float sCf = bC[t] + (float)spc.x;
    float sCc = bC[128 + t] + (float)spc.y;
    float sVf = bC[256 + t] + (float)spv.x;
    float sVc = bC[384 + t] + (float)spv.y;

    const half2_t ONE0 = {(__fp16)1.f, (__fp16)0.f};
    const half2_t ZERO1 = {(__fp16)0.f, (__fp16)1.f};
    int quad = lane >> 4;
    int cla = lane & 15;
    float acc = 0.f;

    #pragma unroll
    for (int h = 0; h < 2; ++h) {
        // ---- phase 1: MFMA contraction into LDS ----
        const _Float16* rf = rfrag + ((size_t)(h * NN + n) * 2) * 512;
        f16x8 a0 = *(const f16x8*)(rf + lane * 8);
        f16x8 a1 = *(const f16x8*)(rf + 512 + lane * 8);
        const f16x8* bw = (const f16x8*)bwc + ((size_t)h * 16) * 64;
        #pragma unroll
        for (int nt = 0; nt < 8; ++nt) {
            int ntg = wv * 8 + nt;
            f16x8 b = bw[(size_t)ntg * 64 + lane];
            f32x4 g0 = {0.f, 0.f, 0.f, 0.f};
            f32x4 g1 = {0.f, 0.f, 0.f, 0.f};
            g0 = __builtin_amdgcn_mfma_f32_16x16x32_f16(a0, b, g0, 0, 0, 0);
            g1 = __builtin_amdgcn_mfma_f32_16x16x32_f16(a1, b, g1, 0, 0, 0);
            int c = ntg * 16 + cla;
            #pragma unroll
            for (int i = 0; i < 4; ++i) {
                G[(quad * 4 + i) * 256 + c] = g0[i];
                G[(16 + quad * 4 + i) * 256 + c] = g1[i];
            }
        }
        __syncthreads();
        // ---- phase 2: per-thread activation over 20 edges ----
        float sf = h ? sVf : sCf;
        float sc = h ? sVc : sCc;
        #pragma unroll
        for (int m = 0; m < MM; ++m) {
            float2 g = *(float2*)&G[m * 256 + 2 * t];
            half2_t w = yw[h * MM + m];
            float gf = fdot2_(w, ONE0, sf + g.x);
            float gc = fdot2_(w, ZERO1, sc + g.y);
            float u = rcp_(1.f + exp2_(-gf));
            float p = log2_(1.f + exp2_(gc));
            p = (gc > 24.f) ? gc : p;
            acc = fmaf(p, u, acc);
        }
        __syncthreads();
    }
    float res = sp_(fmaf(acc, LN2_F, old));
    nodes_out[(size_t)n * HH + t] = res;
    nodes_h[(size_t)n * HH + t] = (_Float16)res;
}

// ---------------- pooling + head MLP ---------------------------------------
__global__ void pool_kernel(const float* __restrict__ nodes, const int* __restrict__ num_atoms,
                            const float* __restrict__ fc1_W, const float* __restrict__ fc1_b,
                            const float* __restrict__ out_W, const float* __restrict__ out_b,
                            float* __restrict__ out) {
    __shared__ float sh[HH];
    __shared__ float red[HH];
    int b = blockIdx.x, t = threadIdx.x;
    int start = 0;
    for (int i = 0; i < b; ++i) start += num_atoms[i];
    int cnt = num_atoms[b];
    float sum = 0.f;
    for (int a = 0; a < cnt; ++a) sum += nodes[(size_t)(start + a) * HH + t];
    float mean = sum / (float)cnt;
    sh[t] = sp_(mean);
    __syncthreads();
    float o = fc1_b[t];
    #pragma unroll 4
    for (int k = 0; k < HH; ++k) o = fmaf(sh[k], fc1_W[k * HH + t], o);
    red[t] = sp_(o) * out_W[t];
    __syncthreads();
    if (t == 0) {
        float tot = 0.f;
        for (int k = 0; k < HH; ++k) tot += red[k];
        out[b] = tot + out_b[0];
    }
}

// ---------------- launch ----------------------------------------------------
extern "C" void kernel_launch(void* const* d_in, const int* in_sizes, int n_in,
                              void* d_out, int out_size, void* d_ws, size_t ws_size,
                              hipStream_t stream) {
    const float* atoms_embed   = (const float*)d_in[0];
    const float* che_nbrs_fea  = (const float*)d_in[1];
    const float* vdw_nbrs_fea  = (const float*)d_in[2];
    const int*   che_nbrs_idx  = (const int*)  d_in[3];
    const int*   vdw_nbrs_idx  = (const int*)  d_in[4];
    const int*   num_atoms     = (const int*)  d_in[5];
    const float* emb_W         = (const float*)d_in[6];
    const float* emb_b         = (const float*)d_in[7];
    const float* che_filter_W  = (const float*)d_in[8];
    const float* che_filter_b  = (const float*)d_in[9];
    const float* che_fc_W      = (const float*)d_in[10];
    const float* che_fc_b      = (const float*)d_in[11];
    const float* vdw_filter_W  = (const float*)d_in[12];
    const float* vdw_filter_b  = (const float*)d_in[13];
    const float* vdw_fc_W      = (const float*)d_in[14];
    const float* vdw_fc_b      = (const float*)d_in[15];
    const float* fc1_W         = (const float*)d_in[16];
    const float* fc1_b         = (const float*)d_in[17];
    const float* out_W         = (const float*)d_in[18];
    const float* out_b         = (const float*)d_in[19];
    float* out = (float*)d_out;

    // workspace layout (~150 MB)
    float* w = (float*)d_ws;
    float* nodesA   = w;                                       // NN*HH f32
    float* nodesB   = nodesA + (size_t)NN * HH;                // NN*HH f32
    _Float16* nodes_h = (_Float16*)(nodesB + (size_t)NN * HH); // NN*HH f16
    half2_t* Spk    = (half2_t*)(nodes_h + (size_t)NN * HH);   // NN*256 words
    half2_t* Ypk    = Spk + (size_t)NN * 256;                  // NN*256 words
    _Float16* rfrag = (_Float16*)(Ypk + (size_t)NN * 256);     // 2*NN*2*512 f16
    _Float16* bpk   = rfrag + (size_t)2 * NN * 2 * 512;        // NCONV*131072 f16
    _Float16* bwc   = bpk + (size_t)NCONV * 131072;            // NCONV*2*16*512 f16
    float* bc       = (float*)(bwc + (size_t)NCONV * 2 * 16 * 512); // NCONV*512 f32

    // zero rfrag so every pad slot the edge MFMA touches is exact 0.0
    // (replay determinism: d_ws is re-poisoned 0xAA before every timed launch)
    hipMemsetAsync(rfrag, 0, (size_t)2 * NN * 2 * 512 * sizeof(_Float16), stream);

    prep_bias<<<dim3(1, 2, NCONV), 256, 0, stream>>>(
        che_filter_b, che_fc_W, che_fc_b, vdw_filter_b, vdw_fc_W, vdw_fc_b, bc);
    prep_bwc<<<dim3(16, 2, NCONV), 512, 0, stream>>>(
        che_filter_W, che_fc_W, vdw_filter_W, vdw_fc_W, bwc);
    prep_bpk<<<(NCONV * 128 * 1024 + 255) / 256, 256, 0, stream>>>(che_fc_W, vdw_fc_W, bpk);
    embed_kernel<<<NN, HH, 0, stream>>>(atoms_embed, emb_W, emb_b, nodesA, nodes_h);
    rbf_kernel<<<(2 * NN * MM + 255) / 256, 256, 0, stream>>>(che_nbrs_fea, vdw_nbrs_fea, rfrag);

    float* cur = nodesA;
    float* nxt = nodesB;
    for (int l = 0; l < NCONV; ++l) {
        gemm_mfma<<<NN / 32, 256, 0, stream>>>(nodes_h, bpk + (size_t)l * 131072, Spk, Ypk);
        edge_kernel<<<NN, HH, 0, stream>>>(
            cur, nxt, nodes_h, Spk, Ypk, rfrag, che_nbrs_idx, vdw_nbrs_idx,
            bwc + (size_t)l * 2 * 16 * 512, bc + (size_t)l * 512);
        float* tmp = cur; cur = nxt; nxt = tmp;
    }

    pool_kernel<<<BB, HH, 0, stream>>>(cur, num_atoms, fc1_W, fc1_b, out_W, out_b, out);
}